// Round 4
// baseline (1071.280 us; speedup 1.0000x reference)
//
#include <hip/hip_runtime.h>
#include <math.h>

#define NN 100000
#define NE 3200000
#define NG 512
#define NBK 782            // dst buckets: ceil(NN/128), bucket = dst>>7
#define EBLK 782           // edge blocks: ceil(NE/4096)
#define STSH 13            // src-tile shift: 8192-node tiles (1MB of a 128B/row slice)
#define NTIL 13            // ceil(NN / 8192)

typedef __attribute__((ext_vector_type(8))) short short8;
typedef __attribute__((ext_vector_type(4))) float f32x4;
typedef __attribute__((ext_vector_type(2))) float f32x2;

// ---------------- bf16 / fp8 helpers ----------------
__device__ __forceinline__ float bf2f(unsigned short h){
  return __uint_as_float(((unsigned int)h) << 16);
}
__device__ __forceinline__ unsigned short f2bf(float f){
  unsigned int u = __float_as_uint(f);
  unsigned int r = (u + 0x7fffu + ((u >> 16) & 1u)) >> 16;   // RNE
  return (unsigned short)r;
}
__device__ __forceinline__ unsigned char f2fp8(float v){
  int p = __builtin_amdgcn_cvt_pk_fp8_f32(v, v, 0, 0);
  return (unsigned char)p;
}

// ---------------- scan-based multi-split CSR build ----------------
// ebuf entries are PACKED: src (17 bits) | dst-within-bucket (7 bits) << 17.
__global__ __launch_bounds__(256) void hist2_k(const int* __restrict__ ei,
    int* __restrict__ cnt, int* __restrict__ btot){
  __shared__ int lh[NBK];
  int t = threadIdx.x, b = blockIdx.x;
  for (int i=t; i<NBK; i+=256) lh[i] = 0;
  __syncthreads();
  int base = b*4096;
  #pragma unroll
  for (int u=0; u<16; u++){
    int e = base + u*256 + t;
    if (e < NE) atomicAdd(&lh[ei[NE + e] >> 7], 1);
  }
  __syncthreads();
  for (int i=t; i<NBK; i+=256){
    int v = lh[i];
    cnt[b*NBK + i] = v;
    if (v) atomicAdd(&btot[i], v);
  }
}
__global__ void bscan2_k(const int* __restrict__ btot, int* __restrict__ bptr){
  __shared__ int sc[1024];
  int t = threadIdx.x;
  int v = (t < NBK) ? btot[t] : 0;
  sc[t] = v; __syncthreads();
  for (int off=1; off<1024; off<<=1){
    int u = (t>=off) ? sc[t-off] : 0;
    __syncthreads(); sc[t] += u; __syncthreads();
  }
  if (t < NBK) bptr[t] = sc[t] - v;
  if (t == 1023) bptr[NBK] = sc[1023];
}
__global__ __launch_bounds__(256) void bkpfx_k(int* __restrict__ cnt, const int* __restrict__ bptr){
  __shared__ int sc[256];
  int b = blockIdx.x, t = threadIdx.x;
  int carry = bptr[b];
  for (int base=0; base<EBLK; base+=256){
    int blk = base + t;
    int v = (blk < EBLK) ? cnt[blk*NBK + b] : 0;
    sc[t] = v; __syncthreads();
    for (int off=1; off<256; off<<=1){
      int u = (t>=off) ? sc[t-off] : 0;
      __syncthreads(); sc[t] += u; __syncthreads();
    }
    if (blk < EBLK) cnt[blk*NBK + b] = carry + sc[t] - v;   // exclusive + base
    carry += sc[255];
    __syncthreads();
  }
}
__global__ __launch_bounds__(256) void scat2_k(const int* __restrict__ ei,
    const int* __restrict__ cnt, unsigned int* __restrict__ ebuf){
  __shared__ int lh[NBK];
  __shared__ int lo[NBK];
  int t = threadIdx.x, b = blockIdx.x;
  for (int i=t; i<NBK; i+=256){ lh[i] = 0; lo[i] = cnt[b*NBK + i]; }
  __syncthreads();
  int base = b*4096;
  #pragma unroll
  for (int u=0; u<16; u++){
    int e = base + u*256 + t;
    if (e < NE){
      int s = ei[e], d = ei[NE + e];
      int bk = d >> 7;
      int r = atomicAdd(&lh[bk], 1);
      ebuf[lo[bk] + r] = (unsigned)s | ((unsigned)(d & 127) << 17);
    }
  }
}
// fused per-bucket CSR finalize: deg count + in-bucket scan -> rp/dinv, then col fill.
// Emits a degree-sorted row permutation within the bucket (perm) for wave load balance.
// col fill is SRC-TILE-PHASED: 13 predicated passes place each row's edges grouped by
// src>>13 ascending. All rows sweep tiles in lockstep-fraction during spmm, so the
// instantaneous gather window is ~1MB -> fits per-XCD L2 and captures the ~32x src
// reuse that previously streamed from DRAM. (Per-row edge order was already
// nondeterministic via atomicAdd arrival; grouping is within that envelope.)
__global__ __launch_bounds__(256) void bcsr_k(const unsigned int* __restrict__ ebuf,
    const int* __restrict__ bptr, int* __restrict__ rp, float* __restrict__ dinv,
    int* __restrict__ col, int* __restrict__ permg){
  __shared__ int cnt[128];
  __shared__ int off[128];
  __shared__ int sc[128];
  __shared__ int dg[128];
  int b = blockIdx.x, t = threadIdx.x;
  int nbase = b << 7;
  int beg = bptr[b], end = bptr[b+1];
  if (t < 128) cnt[t] = 0;
  __syncthreads();
  for (int e = beg + t; e < end; e += 256)
    atomicAdd(&cnt[ebuf[e] >> 17], 1);
  __syncthreads();
  int v = (t < 128) ? cnt[t] : 0;
  if (t < 128){
    sc[t] = v;
    dg[t] = ((nbase + t) < NN) ? v : 0x7FFFFFFF;   // invalid slots sort to bucket end
  }
  __syncthreads();
  for (int o2=1; o2<128; o2<<=1){
    int u = (t < 128 && t >= o2) ? sc[t-o2] : 0;
    __syncthreads();
    if (t < 128) sc[t] += u;
    __syncthreads();
  }
  if (t < 128){
    int node = nbase + t;
    if (node < NN){
      int ex = beg + sc[t] - v;
      rp[node] = ex;
      off[t] = ex;
      dinv[node] = rsqrtf((float)(v + 1));
      cnt[t] = 0;
    }
    // rank of this row by (degree, index) -> degree-sorted perm within bucket
    int d = dg[t];
    int rk = 0;
    #pragma unroll 4
    for (int u=0; u<128; u++){
      int du = dg[u];
      rk += (int)((du < d) || (du == d && u < t));
    }
    permg[nbase + rk] = node;    // node >= NN for pad slots; spmm guards row>=NN
  }
  if (b == ((NN-1) >> 7) && t == 0) rp[NN] = end;
  __syncthreads();
  // src-tile-phased col fill: tile-major, so each row's edges are grouped by src-tile.
  for (int tile = 0; tile < NTIL; tile++){
    for (int e = beg + t; e < end; e += 256){
      unsigned int sd = ebuf[e];
      int src = (int)(sd & 0x1FFFF);
      if ((src >> STSH) != tile) continue;
      int li = sd >> 17;
      int pos = off[li] + atomicAdd(&cnt[li], 1);
      col[pos] = src;
    }
    __syncthreads();
  }
}

// fp32 -> fp8 (4 values/thread)
__global__ void f2q_k(const float* __restrict__ in, unsigned char* __restrict__ out, int n4){
  int i = blockIdx.x*256 + threadIdx.x;
  if (i < n4){
    float4 v = ((const float4*)in)[i];
    int p = __builtin_amdgcn_cvt_pk_fp8_f32(v.x, v.y, 0, 0);
    p = __builtin_amdgcn_cvt_pk_fp8_f32(v.z, v.w, p, 1);
    ((unsigned int*)out)[i] = (unsigned int)p;
  }
}
// all 6 weight swizzles in one launch. blockIdx.y selects config.
// chunk idx = ((kt*(N/16)+nt)*4+q)*16 + l  holds B[k=kt*32+q*8+j][n=nt*16+l], j=0..7
__global__ void wswz_all_k(const float* W1, const float* W2, const float* W3,
                           const float* W4, const float* W5, const float* W6,
                           unsigned short* O1, unsigned short* O2, unsigned short* O3,
                           unsigned short* O4, unsigned short* O5, unsigned short* O6){
  int cfg = blockIdx.y;
  int K, N; const float* W; unsigned short* out;
  switch(cfg){
    case 0: K=128; N=256; W=W1; out=O1; break;
    case 1: K=256; N=256; W=W2; out=O2; break;
    case 2: K=256; N=256; W=W3; out=O3; break;
    case 3: K=256; N=128; W=W4; out=O4; break;
    case 4: K=128; N=128; W=W5; out=O5; break;
    default:K=128; N=64;  W=W6; out=O6; break;
  }
  int idx = blockIdx.x*256 + threadIdx.x;
  int total = K*N/8;
  if (idx >= total) return;
  int l = idx & 15;
  int t = idx >> 4; int q = t & 3; t >>= 2;
  int NT = N/16;
  int nt = t % NT, kt = t / NT;
  int kbase = kt*32 + q*8, n = nt*16 + l;
  short8 o;
  #pragma unroll
  for (int j=0;j<8;j++) o[j] = (short)f2bf(W[(size_t)(kbase+j)*N + n]);
  *(short8*)(out + (size_t)idx*8) = o;
}

// ---------------- fp8 SpMM (packed-pair FMA + LPT wave scheduling) ----------------
// RS = full row stride, W = columns handled by this dispatch slice (blockIdx.y).
// perm[] = rows sorted by degree within each 128-row dst bucket.
// Wave G = blockIdx.x*4+wv handles bucket G%NBK, rank-group (GP-1 - G/NBK):
// high-degree groups go to the EARLIEST blocks (LPT scheduling). Intra-wave rows are
// adjacent ranks (near-equal degree). Edges are src-tile-ordered (see bcsr_k) so all
// concurrent waves gather from a ~1MB sliding window -> L2-resident.
// Accumulation is f32x2 packed (v_pk_fma_f32): 16 VALU instrs/edge vs 24 scalar.
template<int RS, int W, bool SRC_SCALE, bool RELU, bool HAS_BIAS>
__global__ __launch_bounds__(256) void spmm8_k(const unsigned char* __restrict__ in,
    unsigned short* __restrict__ out,
    const int* __restrict__ rp, const int* __restrict__ col,
    const float* __restrict__ dinv, const int* __restrict__ perm,
    const float* __restrict__ bias)
{
  constexpr int LPR = W/16;         // lanes per row
  constexpr int RPW = 64/LPR;       // rows per wave
  constexpr int GP  = 128/RPW;      // rank-groups per bucket
  int tid = threadIdx.x;
  int wv = tid >> 6, lane = tid & 63;
  int sub = lane / LPR, li = lane % LPR;
  int G = blockIdx.x*4 + wv;        // wave linear id over NBK*GP groups
  int bucket = G % NBK;
  int rg = (GP-1) - (G / NBK);      // descending degree: LPT
  int row = perm[(bucket << 7) + rg*RPW + sub];
  if (row >= NN) return;
  int beg = rp[row], end = rp[row+1];
  float di = dinv[row];
  int co = blockIdx.y*W + li*16;
  const unsigned char* inb = in + co;
  f32x2 acc2[8];
  {
    uint4 sv = *(const uint4*)(inb + (size_t)row*RS);   // self loop
    acc2[0] = __builtin_amdgcn_cvt_pk_f32_fp8(sv.x, 0);
    acc2[1] = __builtin_amdgcn_cvt_pk_f32_fp8(sv.x, 1);
    acc2[2] = __builtin_amdgcn_cvt_pk_f32_fp8(sv.y, 0);
    acc2[3] = __builtin_amdgcn_cvt_pk_f32_fp8(sv.y, 1);
    acc2[4] = __builtin_amdgcn_cvt_pk_f32_fp8(sv.z, 0);
    acc2[5] = __builtin_amdgcn_cvt_pk_f32_fp8(sv.z, 1);
    acc2[6] = __builtin_amdgcn_cvt_pk_f32_fp8(sv.w, 0);
    acc2[7] = __builtin_amdgcn_cvt_pk_f32_fp8(sv.w, 1);
    if (SRC_SCALE){
      f32x2 d2 = (f32x2){di, di};
      #pragma unroll
      for (int k=0;k<8;k++) acc2[k] = acc2[k] * d2;
    }
  }
  int j = beg;
  for (; j+8 <= end; j += 8){
    int s[8]; uint4 v[8]; float wgt[8];
    #pragma unroll
    for (int u=0;u<8;u++) s[u] = col[j+u];
    #pragma unroll
    for (int u=0;u<8;u++) v[u] = *(const uint4*)(inb + (size_t)s[u]*RS);
    if (SRC_SCALE){
      #pragma unroll
      for (int u=0;u<8;u++) wgt[u] = dinv[s[u]];
    }
    #pragma unroll
    for (int u=0;u<8;u++){
      float w = SRC_SCALE ? wgt[u] : 1.f;
      f32x2 w2 = (f32x2){w, w};
      acc2[0] = __builtin_elementwise_fma(w2, __builtin_amdgcn_cvt_pk_f32_fp8(v[u].x, 0), acc2[0]);
      acc2[1] = __builtin_elementwise_fma(w2, __builtin_amdgcn_cvt_pk_f32_fp8(v[u].x, 1), acc2[1]);
      acc2[2] = __builtin_elementwise_fma(w2, __builtin_amdgcn_cvt_pk_f32_fp8(v[u].y, 0), acc2[2]);
      acc2[3] = __builtin_elementwise_fma(w2, __builtin_amdgcn_cvt_pk_f32_fp8(v[u].y, 1), acc2[3]);
      acc2[4] = __builtin_elementwise_fma(w2, __builtin_amdgcn_cvt_pk_f32_fp8(v[u].z, 0), acc2[4]);
      acc2[5] = __builtin_elementwise_fma(w2, __builtin_amdgcn_cvt_pk_f32_fp8(v[u].z, 1), acc2[5]);
      acc2[6] = __builtin_elementwise_fma(w2, __builtin_amdgcn_cvt_pk_f32_fp8(v[u].w, 0), acc2[6]);
      acc2[7] = __builtin_elementwise_fma(w2, __builtin_amdgcn_cvt_pk_f32_fp8(v[u].w, 1), acc2[7]);
    }
  }
  for (; j < end; j++){
    int ss = col[j];
    uint4 v = *(const uint4*)(inb + (size_t)ss*RS);
    float w = SRC_SCALE ? dinv[ss] : 1.f;
    f32x2 w2 = (f32x2){w, w};
    acc2[0] = __builtin_elementwise_fma(w2, __builtin_amdgcn_cvt_pk_f32_fp8(v.x, 0), acc2[0]);
    acc2[1] = __builtin_elementwise_fma(w2, __builtin_amdgcn_cvt_pk_f32_fp8(v.x, 1), acc2[1]);
    acc2[2] = __builtin_elementwise_fma(w2, __builtin_amdgcn_cvt_pk_f32_fp8(v.y, 0), acc2[2]);
    acc2[3] = __builtin_elementwise_fma(w2, __builtin_amdgcn_cvt_pk_f32_fp8(v.y, 1), acc2[3]);
    acc2[4] = __builtin_elementwise_fma(w2, __builtin_amdgcn_cvt_pk_f32_fp8(v.z, 0), acc2[4]);
    acc2[5] = __builtin_elementwise_fma(w2, __builtin_amdgcn_cvt_pk_f32_fp8(v.z, 1), acc2[5]);
    acc2[6] = __builtin_elementwise_fma(w2, __builtin_amdgcn_cvt_pk_f32_fp8(v.w, 0), acc2[6]);
    acc2[7] = __builtin_elementwise_fma(w2, __builtin_amdgcn_cvt_pk_f32_fp8(v.w, 1), acc2[7]);
  }
  float acc[16];
  #pragma unroll
  for (int k=0;k<8;k++){ acc[2*k] = acc2[k][0]; acc[2*k+1] = acc2[k][1]; }
  float bb[16];
  if (HAS_BIAS){
    #pragma unroll
    for (int u=0;u<4;u++) *(float4*)&bb[u*4] = *(const float4*)(bias + co + u*4);
  }
  #pragma unroll
  for (int v=0;v<16;v++){
    acc[v] *= di;
    if (HAS_BIAS) acc[v] += bb[v];
    if (RELU) acc[v] = fmaxf(acc[v], 0.f);
  }
  uint4 o0, o1;
  o0.x = (unsigned int)f2bf(acc[0])  | ((unsigned int)f2bf(acc[1])<<16);
  o0.y = (unsigned int)f2bf(acc[2])  | ((unsigned int)f2bf(acc[3])<<16);
  o0.z = (unsigned int)f2bf(acc[4])  | ((unsigned int)f2bf(acc[5])<<16);
  o0.w = (unsigned int)f2bf(acc[6])  | ((unsigned int)f2bf(acc[7])<<16);
  o1.x = (unsigned int)f2bf(acc[8])  | ((unsigned int)f2bf(acc[9])<<16);
  o1.y = (unsigned int)f2bf(acc[10]) | ((unsigned int)f2bf(acc[11])<<16);
  o1.z = (unsigned int)f2bf(acc[12]) | ((unsigned int)f2bf(acc[13])<<16);
  o1.w = (unsigned int)f2bf(acc[14]) | ((unsigned int)f2bf(acc[15])<<16);
  unsigned short* op = out + (size_t)row*RS + co;
  *(uint4*)op = o0;
  *(uint4*)(op + 8) = o1;
}

// ---------------- MFMA bf16 GEMM, stage-once B slice, barrier-free K-loop ----------------
// Grid = dim3(N/64, GX): col-slices vary FASTEST, so the 4 slices sharing one A row-tile
// run concurrently and A re-reads hit L2/L3 instead of HBM.
// Block: 4 waves, 256 rows, 64 cols. K x 64 B-slice (<=32KB LDS) staged once, one barrier,
// then a barrier-free K-loop: 4 ds_read_b128 + 4 prefetched A loads + 16 MFMAs per kt/wave.
// EPI=0: +bias,relu,bf16.  EPI=1: *dinv[row], fp8.
template<int K, int N, int EPI>
__global__ __launch_bounds__(256) void mgemm_k(const unsigned short* __restrict__ A,
    const unsigned short* __restrict__ Bsw,
    const float* __restrict__ aux, unsigned short* __restrict__ Cb,
    unsigned char* __restrict__ Cq, int M)
{
  constexpr int NT = 4;                   // 64 cols = 4 n-tiles
  constexpr int KT = K/32;
  constexpr int NTF = N/16;               // n-tiles in full Bsw
  __shared__ short8 Bl[KT*NT*64];         // K x 64 slice: KT*4*64 short8 = K*64*2 B
  int tid = threadIdx.x;
  int w = tid >> 6, lane = tid & 63;
  int l = lane & 15, q = lane >> 4;
  int nb0 = blockIdx.x * 64;              // col slice (fastest)
  int rb = blockIdx.y*256 + w*64;         // row block
  // stage whole B slice (one barrier)
  {
    const short8* bsrc = (const short8*)Bsw;
    for (int i = tid; i < KT*NT*64; i += 256){
      int kt = i >> 8;                    // /(NT*64)
      int rem = i & 255;
      Bl[i] = bsrc[(kt*NTF + (nb0 >> 4))*64 + rem];
    }
  }
  const unsigned short* ap[4];
  #pragma unroll
  for (int rt=0; rt<4; rt++){
    int r = min(rb + rt*16 + l, M-1);
    ap[rt] = A + (size_t)r*K + q*8;
  }
  f32x4 acc[4][NT];
  #pragma unroll
  for (int rt=0; rt<4; rt++)
    #pragma unroll
    for (int nt=0; nt<NT; nt++) acc[rt][nt] = (f32x4){0,0,0,0};
  short8 a[4], an[4];
  #pragma unroll
  for (int rt=0; rt<4; rt++) a[rt] = *(const short8*)(ap[rt]);
  __syncthreads();
  for (int kt=0; kt<KT; kt++){
    if (kt+1 < KT){
      #pragma unroll
      for (int rt=0; rt<4; rt++) an[rt] = *(const short8*)(ap[rt] + (kt+1)*32);
    }
    const short8* bl = &Bl[kt << 8];
    #pragma unroll
    for (int nt=0; nt<NT; nt++){
      short8 bf = bl[nt*64 + q*16 + l];
      acc[0][nt] = __builtin_amdgcn_mfma_f32_16x16x32_bf16(a[0], bf, acc[0][nt], 0,0,0);
      acc[1][nt] = __builtin_amdgcn_mfma_f32_16x16x32_bf16(a[1], bf, acc[1][nt], 0,0,0);
      acc[2][nt] = __builtin_amdgcn_mfma_f32_16x16x32_bf16(a[2], bf, acc[2][nt], 0,0,0);
      acc[3][nt] = __builtin_amdgcn_mfma_f32_16x16x32_bf16(a[3], bf, acc[3][nt], 0,0,0);
    }
    #pragma unroll
    for (int rt=0; rt<4; rt++) a[rt] = an[rt];
  }
  #pragma unroll
  for (int rt=0; rt<4; rt++){
    int rbb = rb + rt*16;
    #pragma unroll
    for (int nt=0; nt<NT; nt++){
      f32x4 av = acc[rt][nt];
      int n = nb0 + nt*16 + l;
      #pragma unroll
      for (int r=0;r<4;r++){
        int row = rbb + q*4 + r;
        if (row < M){
          float v = av[r];
          if (EPI == 0){
            v = fmaxf(v + aux[n], 0.f);
            Cb[(size_t)row*N + n] = f2bf(v);
          } else {
            v *= aux[row];
            Cq[(size_t)row*N + n] = f2fp8(v);
          }
        }
      }
    }
  }
}

// ---------------- fused mean-pool + linear + (log_)softmax (batch sorted) ----------------
__global__ __launch_bounds__(256) void poolhead_k(const unsigned short* __restrict__ h,
    const int* __restrict__ batch, const float* __restrict__ Wlin,
    const float* __restrict__ blin, float* __restrict__ out)
{
  __shared__ int range[2];
  __shared__ float red[4][64];
  __shared__ float pl[64];
  int g = blockIdx.x;
  if (threadIdx.x < 2){
    int target = g + threadIdx.x;      // lower_bound(batch, target)
    int lo = 0, hi = NN;
    while (lo < hi){ int m = (lo+hi) >> 1; if (batch[m] < target) lo = m+1; else hi = m; }
    range[threadIdx.x] = lo;
  }
  __syncthreads();
  int lo = range[0], hi = range[1];
  int ch = threadIdx.x & 63, rg = threadIdx.x >> 6;
  float s = 0.f;
  for (int r = lo + rg; r < hi; r += 4) s += bf2f(h[(size_t)r*64 + ch]);
  red[rg][ch] = s; __syncthreads();
  if (rg == 0){
    float tot = red[0][ch] + red[1][ch] + red[2][ch] + red[3][ch];
    pl[ch] = tot / fmaxf((float)(hi - lo), 1.f);
  }
  __syncthreads();
  if (threadIdx.x == 0){
    float l[10];
    #pragma unroll
    for (int j=0;j<10;j++) l[j] = blin[j];
    for (int c=0;c<64;c++){
      float p = pl[c];
      #pragma unroll
      for (int j=0;j<10;j++) l[j] = fmaf(p, Wlin[c*10 + j], l[j]);
    }
    float mx = l[0];
    #pragma unroll
    for (int j=1;j<10;j++) mx = fmaxf(mx, l[j]);
    float e[10]; float se = 0.f;
    #pragma unroll
    for (int j=0;j<10;j++){ e[j] = expf(l[j]-mx); se += e[j]; }
    float lse = logf(se);
    #pragma unroll
    for (int j=0;j<10;j++){
      out[g*10 + j]         = l[j] - mx - lse;   // log_softmax
      out[NG*10 + g*10 + j] = e[j] / se;         // softmax
    }
  }
}

// ---------------- launch ----------------
extern "C" void kernel_launch(void* const* d_in, const int* in_sizes, int n_in,
                              void* d_out, int out_size, void* d_ws, size_t ws_size,
                              hipStream_t stream)
{
  const float* x     = (const float*)d_in[0];
  const int*   ei    = (const int*)  d_in[1];
  const int*   batch = (const int*)  d_in[2];
  const float* W1=(const float*)d_in[4],  *b1=(const float*)d_in[5];
  const float* W2=(const float*)d_in[6],  *b2=(const float*)d_in[7];
  const float* W3=(const float*)d_in[8],  *b3=(const float*)d_in[9];
  const float* W4=(const float*)d_in[10], *b4=(const float*)d_in[11];
  const float* W5=(const float*)d_in[12], *b5=(const float*)d_in[13];
  const float* W6=(const float*)d_in[14], *b6=(const float*)d_in[15];
  const float* Wl=(const float*)d_in[16], *bl=(const float*)d_in[17];
  float* out = (float*)d_out;

  char* ws = (char*)d_ws;
  unsigned short* hA  = (unsigned short*)(ws + 0);            // bf16 51,200,000
  unsigned short* hB  = (unsigned short*)(ws + 51200000);     // bf16 51,200,000
  unsigned char*  hQ  = (unsigned char*) (ws + 102400000);    // fp8  25,600,000
  unsigned char*  xq  = (unsigned char*) (ws + 128000000);    // fp8  12,800,000
  int*   col   = (int*)  (ws + 140800000);                    // 12,800,000
  unsigned int* ebuf = (unsigned int*)(ws + 153600000);       // 12,800,000 (packed)
  int*   rp    = (int*)  (ws + 166400000);                    // 400,016
  float* dinv  = (float*)(ws + 166800016);                    // 400,000
  unsigned short* W1s = (unsigned short*)(ws + 167200016);    // 65,536
  unsigned short* W2s = (unsigned short*)(ws + 167265552);    // 131,072
  unsigned short* W3s = (unsigned short*)(ws + 167396624);    // 131,072
  unsigned short* W4s = (unsigned short*)(ws + 167527696);    // 65,536
  unsigned short* W5s = (unsigned short*)(ws + 167593232);    // 32,768
  unsigned short* W6s = (unsigned short*)(ws + 167626000);    // 16,384
  int*   btot  = (int*)  (ws + 167642896);                    // 3,128
  int*   bptr  = (int*)  (ws + 167646032);                    // 3,132
  int*   cnt   = (int*)  (ws + 167649184);                    // 782*782*4 = 2,446,096
  // perm overlaps cnt: cnt's last reader is scat2_k, bcsr_k (writer of perm) runs after.
  int*   perm  = cnt;                                         // NBK*128 = 100,096 ints

  hipMemsetAsync(btot, 0, NBK*4, stream);

  // scan-based multi-split CSR build (no high-contention atomics)
  hist2_k <<<EBLK, 256, 0, stream>>>(ei, cnt, btot);
  bscan2_k<<<1, 1024, 0, stream>>>(btot, bptr);
  bkpfx_k <<<NBK, 256, 0, stream>>>(cnt, bptr);
  scat2_k <<<EBLK, 256, 0, stream>>>(ei, cnt, ebuf);
  bcsr_k  <<<NBK, 256, 0, stream>>>(ebuf, bptr, rp, dinv, col, perm);

  wswz_all_k<<<dim3(32,6), 256, 0, stream>>>(W1,W2,W3,W4,W5,W6, W1s,W2s,W3s,W4s,W5s,W6s);
  f2q_k<<<(NN*128/4 + 255)/256, 256, 0, stream>>>(x, xq, NN*128/4);

  const int GX128 = NBK*16/4;   // W=128: 16 wave-groups/bucket, 4 waves/block = 3128
  const int GX64  = NBK*8/4;    // W=64:   8 wave-groups/bucket -> 1564
  const int GX    = (NN + 255)/256;    // gemm row-blocks (256 rows each)

  // L1: aggregate-first at width 128 (Â x, fp8 gather), then GEMM 128->256 (+b1, relu, bf16)
  spmm8_k<128,128,true,false,false><<<dim3(GX128,1),256,0,stream>>>(xq, hA, rp, col, dinv, perm, nullptr);
  mgemm_k<128,256,0><<<dim3(4,GX),256,0,stream>>>(hA, W1s, b1, hB, nullptr, NN);
  // L2: GEMM (*dinv -> fp8), spmm fp8 gather split into two 128-col slices (+b2, relu -> bf16)
  mgemm_k<256,256,1><<<dim3(4,GX),256,0,stream>>>(hB, W2s, dinv, nullptr, hQ, NN);
  spmm8_k<256,128,false,true,true><<<dim3(GX128,2),256,0,stream>>>(hQ, hA, rp, col, dinv, perm, b2);
  // L3
  mgemm_k<256,256,1><<<dim3(4,GX),256,0,stream>>>(hA, W3s, dinv, nullptr, hQ, NN);
  spmm8_k<256,128,false,true,true><<<dim3(GX128,2),256,0,stream>>>(hQ, hB, rp, col, dinv, perm, b3);
  // L4: 256->128
  mgemm_k<256,128,1><<<dim3(2,GX),256,0,stream>>>(hB, W4s, dinv, nullptr, hQ, NN);
  spmm8_k<128,128,false,true,true><<<dim3(GX128,1),256,0,stream>>>(hQ, hA, rp, col, dinv, perm, b4);
  // L5: 128->128
  mgemm_k<128,128,1><<<dim3(2,GX),256,0,stream>>>(hA, W5s, dinv, nullptr, hQ, NN);
  spmm8_k<128,128,false,true,true><<<dim3(GX128,1),256,0,stream>>>(hQ, hB, rp, col, dinv, perm, b5);
  // L6: 128->64, no relu
  mgemm_k<128,64,1><<<dim3(1,GX),256,0,stream>>>(hB, W6s, dinv, nullptr, hQ, NN);
  spmm8_k<64,64,false,false,true><<<dim3(GX64,1),256,0,stream>>>(hQ, hA, rp, col, dinv, perm, b6);

  // fused deterministic mean-pool + head
  poolhead_k<<<NG, 256, 0, stream>>>(hA, batch, Wl, bl, out);
}

// Round 5
// 1027.409 us; speedup vs baseline: 1.0427x; 1.0427x over previous
//
#include <hip/hip_runtime.h>
#include <math.h>

#define NN 100000
#define NE 3200000
#define NG 512
#define NBK 782            // dst buckets: ceil(NN/128), bucket = dst>>7
#define EBLK 782           // edge blocks: ceil(NE/4096)
#define STSH 13            // src-tile shift: 8192-node tiles (1MB of a 128B/row slice)
#define NTIL 13            // ceil(NN / 8192)

typedef __attribute__((ext_vector_type(8))) short short8;
typedef __attribute__((ext_vector_type(4))) float f32x4;
typedef __attribute__((ext_vector_type(2))) float f32x2;

// ---------------- bf16 / fp8 helpers ----------------
__device__ __forceinline__ float bf2f(unsigned short h){
  return __uint_as_float(((unsigned int)h) << 16);
}
__device__ __forceinline__ unsigned short f2bf(float f){
  unsigned int u = __float_as_uint(f);
  unsigned int r = (u + 0x7fffu + ((u >> 16) & 1u)) >> 16;   // RNE
  return (unsigned short)r;
}
__device__ __forceinline__ unsigned char f2fp8(float v){
  int p = __builtin_amdgcn_cvt_pk_fp8_f32(v, v, 0, 0);
  return (unsigned char)p;
}

// ---------------- scan-based multi-split CSR build ----------------
// ebuf entries are PACKED: src (17 bits) | dst-within-bucket (7 bits) << 17.
__global__ __launch_bounds__(256) void hist2_k(const int* __restrict__ ei,
    int* __restrict__ cnt, int* __restrict__ btot){
  __shared__ int lh[NBK];
  int t = threadIdx.x, b = blockIdx.x;
  for (int i=t; i<NBK; i+=256) lh[i] = 0;
  __syncthreads();
  int base = b*4096;
  #pragma unroll
  for (int u=0; u<16; u++){
    int e = base + u*256 + t;
    if (e < NE) atomicAdd(&lh[ei[NE + e] >> 7], 1);
  }
  __syncthreads();
  for (int i=t; i<NBK; i+=256){
    int v = lh[i];
    cnt[b*NBK + i] = v;
    if (v) atomicAdd(&btot[i], v);
  }
}
__global__ void bscan2_k(const int* __restrict__ btot, int* __restrict__ bptr){
  __shared__ int sc[1024];
  int t = threadIdx.x;
  int v = (t < NBK) ? btot[t] : 0;
  sc[t] = v; __syncthreads();
  for (int off=1; off<1024; off<<=1){
    int u = (t>=off) ? sc[t-off] : 0;
    __syncthreads(); sc[t] += u; __syncthreads();
  }
  if (t < NBK) bptr[t] = sc[t] - v;
  if (t == 1023) bptr[NBK] = sc[1023];
}
__global__ __launch_bounds__(256) void bkpfx_k(int* __restrict__ cnt, const int* __restrict__ bptr){
  __shared__ int sc[256];
  int b = blockIdx.x, t = threadIdx.x;
  int carry = bptr[b];
  for (int base=0; base<EBLK; base+=256){
    int blk = base + t;
    int v = (blk < EBLK) ? cnt[blk*NBK + b] : 0;
    sc[t] = v; __syncthreads();
    for (int off=1; off<256; off<<=1){
      int u = (t>=off) ? sc[t-off] : 0;
      __syncthreads(); sc[t] += u; __syncthreads();
    }
    if (blk < EBLK) cnt[blk*NBK + b] = carry + sc[t] - v;   // exclusive + base
    carry += sc[255];
    __syncthreads();
  }
}
__global__ __launch_bounds__(256) void scat2_k(const int* __restrict__ ei,
    const int* __restrict__ cnt, unsigned int* __restrict__ ebuf){
  __shared__ int lh[NBK];
  __shared__ int lo[NBK];
  int t = threadIdx.x, b = blockIdx.x;
  for (int i=t; i<NBK; i+=256){ lh[i] = 0; lo[i] = cnt[b*NBK + i]; }
  __syncthreads();
  int base = b*4096;
  #pragma unroll
  for (int u=0; u<16; u++){
    int e = base + u*256 + t;
    if (e < NE){
      int s = ei[e], d = ei[NE + e];
      int bk = d >> 7;
      int r = atomicAdd(&lh[bk], 1);
      ebuf[lo[bk] + r] = (unsigned)s | ((unsigned)(d & 127) << 17);
    }
  }
}
// fused per-bucket CSR finalize: per-(row,tile) count + scan -> rp/dinv/col, 2 passes
// over ebuf total. col layout is src-tile-grouped per row (same as the 13-pass R4
// version, at pre-R4 cost): tiles ascending within each row's edge segment.
// Also emits the degree-sorted row permutation (perm) for wave load balance.
__global__ __launch_bounds__(256) void bcsr_k(const unsigned int* __restrict__ ebuf,
    const int* __restrict__ bptr, int* __restrict__ rp, float* __restrict__ dinv,
    int* __restrict__ col, int* __restrict__ permg){
  __shared__ int cnt2[128*NTIL];   // per (li,tile) counts -> absolute running offsets
  __shared__ int sc[128];
  __shared__ int dg[128];
  int b = blockIdx.x, t = threadIdx.x;
  int nbase = b << 7;
  int beg = bptr[b], end = bptr[b+1];
  for (int i = t; i < 128*NTIL; i += 256) cnt2[i] = 0;
  __syncthreads();
  for (int e = beg + t; e < end; e += 256){
    unsigned int sd = ebuf[e];
    int li = sd >> 17;
    int tile = (int)(sd & 0x1FFFFu) >> STSH;
    atomicAdd(&cnt2[li*NTIL + tile], 1);
  }
  __syncthreads();
  int v = 0;
  if (t < 128){
    #pragma unroll
    for (int k=0;k<NTIL;k++) v += cnt2[t*NTIL+k];
    sc[t] = v;
    dg[t] = ((nbase + t) < NN) ? v : 0x7FFFFFFF;   // invalid slots sort to bucket end
  }
  __syncthreads();
  for (int o2=1; o2<128; o2<<=1){
    int u = (t < 128 && t >= o2) ? sc[t-o2] : 0;
    __syncthreads();
    if (t < 128) sc[t] += u;
    __syncthreads();
  }
  if (t < 128){
    int node = nbase + t;
    int ex = beg + sc[t] - v;          // exclusive row start
    if (node < NN){
      rp[node] = ex;
      dinv[node] = rsqrtf((float)(v + 1));
    }
    // convert this row's tile counts into absolute running start offsets
    int s = ex;
    #pragma unroll
    for (int k=0;k<NTIL;k++){
      int c = cnt2[t*NTIL+k];
      cnt2[t*NTIL+k] = s;
      s += c;
    }
    // rank of this row by (degree, index) -> degree-sorted perm within bucket
    int d = dg[t];
    int rk = 0;
    #pragma unroll 4
    for (int u2=0; u2<128; u2++){
      int du = dg[u2];
      rk += (int)((du < d) || (du == d && u2 < t));
    }
    permg[nbase + rk] = node;    // node >= NN for pad slots; spmm guards row>=NN
  }
  if (b == ((NN-1) >> 7) && t == 0) rp[NN] = end;
  __syncthreads();
  for (int e = beg + t; e < end; e += 256){
    unsigned int sd = ebuf[e];
    int li = sd >> 17;
    int src = (int)(sd & 0x1FFFF);
    int tile = src >> STSH;
    int pos = atomicAdd(&cnt2[li*NTIL + tile], 1);
    col[pos] = src;
  }
}

// fp32 -> fp8 (4 values/thread)
__global__ void f2q_k(const float* __restrict__ in, unsigned char* __restrict__ out, int n4){
  int i = blockIdx.x*256 + threadIdx.x;
  if (i < n4){
    float4 v = ((const float4*)in)[i];
    int p = __builtin_amdgcn_cvt_pk_fp8_f32(v.x, v.y, 0, 0);
    p = __builtin_amdgcn_cvt_pk_fp8_f32(v.z, v.w, p, 1);
    ((unsigned int*)out)[i] = (unsigned int)p;
  }
}
// all 6 weight swizzles in one launch. blockIdx.y selects config.
// chunk idx = ((kt*(N/16)+nt)*4+q)*16 + l  holds B[k=kt*32+q*8+j][n=nt*16+l], j=0..7
__global__ void wswz_all_k(const float* W1, const float* W2, const float* W3,
                           const float* W4, const float* W5, const float* W6,
                           unsigned short* O1, unsigned short* O2, unsigned short* O3,
                           unsigned short* O4, unsigned short* O5, unsigned short* O6){
  int cfg = blockIdx.y;
  int K, N; const float* W; unsigned short* out;
  switch(cfg){
    case 0: K=128; N=256; W=W1; out=O1; break;
    case 1: K=256; N=256; W=W2; out=O2; break;
    case 2: K=256; N=256; W=W3; out=O3; break;
    case 3: K=256; N=128; W=W4; out=O4; break;
    case 4: K=128; N=128; W=W5; out=O5; break;
    default:K=128; N=64;  W=W6; out=O6; break;
  }
  int idx = blockIdx.x*256 + threadIdx.x;
  int total = K*N/8;
  if (idx >= total) return;
  int l = idx & 15;
  int t = idx >> 4; int q = t & 3; t >>= 2;
  int NT = N/16;
  int nt = t % NT, kt = t / NT;
  int kbase = kt*32 + q*8, n = nt*16 + l;
  short8 o;
  #pragma unroll
  for (int j=0;j<8;j++) o[j] = (short)f2bf(W[(size_t)(kbase+j)*N + n]);
  *(short8*)(out + (size_t)idx*8) = o;
}

// ---------------- fp8 SpMM (packed-pair FMA + LPT wave scheduling) ----------------
// RS = full row stride, W = columns handled by this dispatch slice (blockIdx.y).
// perm[] = rows sorted by degree within each 128-row dst bucket.
// Wave G = blockIdx.x*4+wv handles bucket G%NBK, rank-group (GP-1 - G/NBK):
// high-degree groups go to the EARLIEST blocks (LPT scheduling). Intra-wave rows are
// adjacent ranks (near-equal degree). Edges are src-tile-ordered (see bcsr_k).
// Accumulation is f32x2 packed (v_pk_fma_f32): 16 VALU instrs/edge vs 24 scalar.
template<int RS, int W, bool SRC_SCALE, bool RELU, bool HAS_BIAS>
__global__ __launch_bounds__(256) void spmm8_k(const unsigned char* __restrict__ in,
    unsigned short* __restrict__ out,
    const int* __restrict__ rp, const int* __restrict__ col,
    const float* __restrict__ dinv, const int* __restrict__ perm,
    const float* __restrict__ bias)
{
  constexpr int LPR = W/16;         // lanes per row
  constexpr int RPW = 64/LPR;       // rows per wave
  constexpr int GP  = 128/RPW;      // rank-groups per bucket
  int tid = threadIdx.x;
  int wv = tid >> 6, lane = tid & 63;
  int sub = lane / LPR, li = lane % LPR;
  int G = blockIdx.x*4 + wv;        // wave linear id over NBK*GP groups
  int bucket = G % NBK;
  int rg = (GP-1) - (G / NBK);      // descending degree: LPT
  int row = perm[(bucket << 7) + rg*RPW + sub];
  if (row >= NN) return;
  int beg = rp[row], end = rp[row+1];
  float di = dinv[row];
  int co = blockIdx.y*W + li*16;
  const unsigned char* inb = in + co;
  f32x2 acc2[8];
  {
    uint4 sv = *(const uint4*)(inb + (size_t)row*RS);   // self loop
    acc2[0] = __builtin_amdgcn_cvt_pk_f32_fp8(sv.x, 0);
    acc2[1] = __builtin_amdgcn_cvt_pk_f32_fp8(sv.x, 1);
    acc2[2] = __builtin_amdgcn_cvt_pk_f32_fp8(sv.y, 0);
    acc2[3] = __builtin_amdgcn_cvt_pk_f32_fp8(sv.y, 1);
    acc2[4] = __builtin_amdgcn_cvt_pk_f32_fp8(sv.z, 0);
    acc2[5] = __builtin_amdgcn_cvt_pk_f32_fp8(sv.z, 1);
    acc2[6] = __builtin_amdgcn_cvt_pk_f32_fp8(sv.w, 0);
    acc2[7] = __builtin_amdgcn_cvt_pk_f32_fp8(sv.w, 1);
    if (SRC_SCALE){
      f32x2 d2 = (f32x2){di, di};
      #pragma unroll
      for (int k=0;k<8;k++) acc2[k] = acc2[k] * d2;
    }
  }
  int j = beg;
  for (; j+8 <= end; j += 8){
    int s[8]; uint4 v[8]; float wgt[8];
    #pragma unroll
    for (int u=0;u<8;u++) s[u] = col[j+u];
    #pragma unroll
    for (int u=0;u<8;u++) v[u] = *(const uint4*)(inb + (size_t)s[u]*RS);
    if (SRC_SCALE){
      #pragma unroll
      for (int u=0;u<8;u++) wgt[u] = dinv[s[u]];
    }
    #pragma unroll
    for (int u=0;u<8;u++){
      float w = SRC_SCALE ? wgt[u] : 1.f;
      f32x2 w2 = (f32x2){w, w};
      acc2[0] = __builtin_elementwise_fma(w2, __builtin_amdgcn_cvt_pk_f32_fp8(v[u].x, 0), acc2[0]);
      acc2[1] = __builtin_elementwise_fma(w2, __builtin_amdgcn_cvt_pk_f32_fp8(v[u].x, 1), acc2[1]);
      acc2[2] = __builtin_elementwise_fma(w2, __builtin_amdgcn_cvt_pk_f32_fp8(v[u].y, 0), acc2[2]);
      acc2[3] = __builtin_elementwise_fma(w2, __builtin_amdgcn_cvt_pk_f32_fp8(v[u].y, 1), acc2[3]);
      acc2[4] = __builtin_elementwise_fma(w2, __builtin_amdgcn_cvt_pk_f32_fp8(v[u].z, 0), acc2[4]);
      acc2[5] = __builtin_elementwise_fma(w2, __builtin_amdgcn_cvt_pk_f32_fp8(v[u].z, 1), acc2[5]);
      acc2[6] = __builtin_elementwise_fma(w2, __builtin_amdgcn_cvt_pk_f32_fp8(v[u].w, 0), acc2[6]);
      acc2[7] = __builtin_elementwise_fma(w2, __builtin_amdgcn_cvt_pk_f32_fp8(v[u].w, 1), acc2[7]);
    }
  }
  for (; j < end; j++){
    int ss = col[j];
    uint4 v = *(const uint4*)(inb + (size_t)ss*RS);
    float w = SRC_SCALE ? dinv[ss] : 1.f;
    f32x2 w2 = (f32x2){w, w};
    acc2[0] = __builtin_elementwise_fma(w2, __builtin_amdgcn_cvt_pk_f32_fp8(v.x, 0), acc2[0]);
    acc2[1] = __builtin_elementwise_fma(w2, __builtin_amdgcn_cvt_pk_f32_fp8(v.x, 1), acc2[1]);
    acc2[2] = __builtin_elementwise_fma(w2, __builtin_amdgcn_cvt_pk_f32_fp8(v.y, 0), acc2[2]);
    acc2[3] = __builtin_elementwise_fma(w2, __builtin_amdgcn_cvt_pk_f32_fp8(v.y, 1), acc2[3]);
    acc2[4] = __builtin_elementwise_fma(w2, __builtin_amdgcn_cvt_pk_f32_fp8(v.z, 0), acc2[4]);
    acc2[5] = __builtin_elementwise_fma(w2, __builtin_amdgcn_cvt_pk_f32_fp8(v.z, 1), acc2[5]);
    acc2[6] = __builtin_elementwise_fma(w2, __builtin_amdgcn_cvt_pk_f32_fp8(v.w, 0), acc2[6]);
    acc2[7] = __builtin_elementwise_fma(w2, __builtin_amdgcn_cvt_pk_f32_fp8(v.w, 1), acc2[7]);
  }
  float acc[16];
  #pragma unroll
  for (int k=0;k<8;k++){ acc[2*k] = acc2[k][0]; acc[2*k+1] = acc2[k][1]; }
  float bb[16];
  if (HAS_BIAS){
    #pragma unroll
    for (int u=0;u<4;u++) *(float4*)&bb[u*4] = *(const float4*)(bias + co + u*4);
  }
  #pragma unroll
  for (int v=0;v<16;v++){
    acc[v] *= di;
    if (HAS_BIAS) acc[v] += bb[v];
    if (RELU) acc[v] = fmaxf(acc[v], 0.f);
  }
  uint4 o0, o1;
  o0.x = (unsigned int)f2bf(acc[0])  | ((unsigned int)f2bf(acc[1])<<16);
  o0.y = (unsigned int)f2bf(acc[2])  | ((unsigned int)f2bf(acc[3])<<16);
  o0.z = (unsigned int)f2bf(acc[4])  | ((unsigned int)f2bf(acc[5])<<16);
  o0.w = (unsigned int)f2bf(acc[6])  | ((unsigned int)f2bf(acc[7])<<16);
  o1.x = (unsigned int)f2bf(acc[8])  | ((unsigned int)f2bf(acc[9])<<16);
  o1.y = (unsigned int)f2bf(acc[10]) | ((unsigned int)f2bf(acc[11])<<16);
  o1.z = (unsigned int)f2bf(acc[12]) | ((unsigned int)f2bf(acc[13])<<16);
  o1.w = (unsigned int)f2bf(acc[14]) | ((unsigned int)f2bf(acc[15])<<16);
  unsigned short* op = out + (size_t)row*RS + co;
  *(uint4*)op = o0;
  *(uint4*)(op + 8) = o1;
}

// ---------------- MFMA bf16 GEMM, stage-once B slice, barrier-free K-loop ----------------
// Grid = dim3(N/64, GX): col-slices vary FASTEST, so the 4 slices sharing one A row-tile
// run concurrently and A re-reads hit L2/L3 instead of HBM.
// Block: 4 waves, 256 rows, 64 cols. K x 64 B-slice (<=32KB LDS) staged once, one barrier,
// then a barrier-free K-loop: 4 ds_read_b128 + 4 prefetched A loads + 16 MFMAs per kt/wave.
// EPI=0: +bias,relu,bf16.  EPI=1: *dinv[row], fp8.
template<int K, int N, int EPI>
__global__ __launch_bounds__(256) void mgemm_k(const unsigned short* __restrict__ A,
    const unsigned short* __restrict__ Bsw,
    const float* __restrict__ aux, unsigned short* __restrict__ Cb,
    unsigned char* __restrict__ Cq, int M)
{
  constexpr int NT = 4;                   // 64 cols = 4 n-tiles
  constexpr int KT = K/32;
  constexpr int NTF = N/16;               // n-tiles in full Bsw
  __shared__ short8 Bl[KT*NT*64];         // K x 64 slice: KT*4*64 short8 = K*64*2 B
  int tid = threadIdx.x;
  int w = tid >> 6, lane = tid & 63;
  int l = lane & 15, q = lane >> 4;
  int nb0 = blockIdx.x * 64;              // col slice (fastest)
  int rb = blockIdx.y*256 + w*64;         // row block
  // stage whole B slice (one barrier)
  {
    const short8* bsrc = (const short8*)Bsw;
    for (int i = tid; i < KT*NT*64; i += 256){
      int kt = i >> 8;                    // /(NT*64)
      int rem = i & 255;
      Bl[i] = bsrc[(kt*NTF + (nb0 >> 4))*64 + rem];
    }
  }
  const unsigned short* ap[4];
  #pragma unroll
  for (int rt=0; rt<4; rt++){
    int r = min(rb + rt*16 + l, M-1);
    ap[rt] = A + (size_t)r*K + q*8;
  }
  f32x4 acc[4][NT];
  #pragma unroll
  for (int rt=0; rt<4; rt++)
    #pragma unroll
    for (int nt=0; nt<NT; nt++) acc[rt][nt] = (f32x4){0,0,0,0};
  short8 a[4], an[4];
  #pragma unroll
  for (int rt=0; rt<4; rt++) a[rt] = *(const short8*)(ap[rt]);
  __syncthreads();
  for (int kt=0; kt<KT; kt++){
    if (kt+1 < KT){
      #pragma unroll
      for (int rt=0; rt<4; rt++) an[rt] = *(const short8*)(ap[rt] + (kt+1)*32);
    }
    const short8* bl = &Bl[kt << 8];
    #pragma unroll
    for (int nt=0; nt<NT; nt++){
      short8 bf = bl[nt*64 + q*16 + l];
      acc[0][nt] = __builtin_amdgcn_mfma_f32_16x16x32_bf16(a[0], bf, acc[0][nt], 0,0,0);
      acc[1][nt] = __builtin_amdgcn_mfma_f32_16x16x32_bf16(a[1], bf, acc[1][nt], 0,0,0);
      acc[2][nt] = __builtin_amdgcn_mfma_f32_16x16x32_bf16(a[2], bf, acc[2][nt], 0,0,0);
      acc[3][nt] = __builtin_amdgcn_mfma_f32_16x16x32_bf16(a[3], bf, acc[3][nt], 0,0,0);
    }
    #pragma unroll
    for (int rt=0; rt<4; rt++) a[rt] = an[rt];
  }
  #pragma unroll
  for (int rt=0; rt<4; rt++){
    int rbb = rb + rt*16;
    #pragma unroll
    for (int nt=0; nt<NT; nt++){
      f32x4 av = acc[rt][nt];
      int n = nb0 + nt*16 + l;
      #pragma unroll
      for (int r=0;r<4;r++){
        int row = rbb + q*4 + r;
        if (row < M){
          float v = av[r];
          if (EPI == 0){
            v = fmaxf(v + aux[n], 0.f);
            Cb[(size_t)row*N + n] = f2bf(v);
          } else {
            v *= aux[row];
            Cq[(size_t)row*N + n] = f2fp8(v);
          }
        }
      }
    }
  }
}

// ---------------- fused mean-pool + linear + (log_)softmax (batch sorted) ----------------
__global__ __launch_bounds__(256) void poolhead_k(const unsigned short* __restrict__ h,
    const int* __restrict__ batch, const float* __restrict__ Wlin,
    const float* __restrict__ blin, float* __restrict__ out)
{
  __shared__ int range[2];
  __shared__ float red[4][64];
  __shared__ float pl[64];
  int g = blockIdx.x;
  if (threadIdx.x < 2){
    int target = g + threadIdx.x;      // lower_bound(batch, target)
    int lo = 0, hi = NN;
    while (lo < hi){ int m = (lo+hi) >> 1; if (batch[m] < target) lo = m+1; else hi = m; }
    range[threadIdx.x] = lo;
  }
  __syncthreads();
  int lo = range[0], hi = range[1];
  int ch = threadIdx.x & 63, rg = threadIdx.x >> 6;
  float s = 0.f;
  for (int r = lo + rg; r < hi; r += 4) s += bf2f(h[(size_t)r*64 + ch]);
  red[rg][ch] = s; __syncthreads();
  if (rg == 0){
    float tot = red[0][ch] + red[1][ch] + red[2][ch] + red[3][ch];
    pl[ch] = tot / fmaxf((float)(hi - lo), 1.f);
  }
  __syncthreads();
  if (threadIdx.x == 0){
    float l[10];
    #pragma unroll
    for (int j=0;j<10;j++) l[j] = blin[j];
    for (int c=0;c<64;c++){
      float p = pl[c];
      #pragma unroll
      for (int j=0;j<10;j++) l[j] = fmaf(p, Wlin[c*10 + j], l[j]);
    }
    float mx = l[0];
    #pragma unroll
    for (int j=1;j<10;j++) mx = fmaxf(mx, l[j]);
    float e[10]; float se = 0.f;
    #pragma unroll
    for (int j=0;j<10;j++){ e[j] = expf(l[j]-mx); se += e[j]; }
    float lse = logf(se);
    #pragma unroll
    for (int j=0;j<10;j++){
      out[g*10 + j]         = l[j] - mx - lse;   // log_softmax
      out[NG*10 + g*10 + j] = e[j] / se;         // softmax
    }
  }
}

// ---------------- launch ----------------
extern "C" void kernel_launch(void* const* d_in, const int* in_sizes, int n_in,
                              void* d_out, int out_size, void* d_ws, size_t ws_size,
                              hipStream_t stream)
{
  const float* x     = (const float*)d_in[0];
  const int*   ei    = (const int*)  d_in[1];
  const int*   batch = (const int*)  d_in[2];
  const float* W1=(const float*)d_in[4],  *b1=(const float*)d_in[5];
  const float* W2=(const float*)d_in[6],  *b2=(const float*)d_in[7];
  const float* W3=(const float*)d_in[8],  *b3=(const float*)d_in[9];
  const float* W4=(const float*)d_in[10], *b4=(const float*)d_in[11];
  const float* W5=(const float*)d_in[12], *b5=(const float*)d_in[13];
  const float* W6=(const float*)d_in[14], *b6=(const float*)d_in[15];
  const float* Wl=(const float*)d_in[16], *bl=(const float*)d_in[17];
  float* out = (float*)d_out;

  char* ws = (char*)d_ws;
  unsigned short* hA  = (unsigned short*)(ws + 0);            // bf16 51,200,000
  unsigned short* hB  = (unsigned short*)(ws + 51200000);     // bf16 51,200,000
  unsigned char*  hQ  = (unsigned char*) (ws + 102400000);    // fp8  25,600,000
  unsigned char*  xq  = (unsigned char*) (ws + 128000000);    // fp8  12,800,000
  int*   col   = (int*)  (ws + 140800000);                    // 12,800,000
  unsigned int* ebuf = (unsigned int*)(ws + 153600000);       // 12,800,000 (packed)
  int*   rp    = (int*)  (ws + 166400000);                    // 400,016
  float* dinv  = (float*)(ws + 166800016);                    // 400,000
  unsigned short* W1s = (unsigned short*)(ws + 167200016);    // 65,536
  unsigned short* W2s = (unsigned short*)(ws + 167265552);    // 131,072
  unsigned short* W3s = (unsigned short*)(ws + 167396624);    // 131,072
  unsigned short* W4s = (unsigned short*)(ws + 167527696);    // 65,536
  unsigned short* W5s = (unsigned short*)(ws + 167593232);    // 32,768
  unsigned short* W6s = (unsigned short*)(ws + 167626000);    // 16,384
  int*   btot  = (int*)  (ws + 167642896);                    // 3,128
  int*   bptr  = (int*)  (ws + 167646032);                    // 3,132
  int*   cnt   = (int*)  (ws + 167649184);                    // 782*782*4 = 2,446,096
  // perm overlaps cnt: cnt's last reader is scat2_k, bcsr_k (writer of perm) runs after.
  int*   perm  = cnt;                                         // NBK*128 = 100,096 ints

  hipMemsetAsync(btot, 0, NBK*4, stream);

  // scan-based multi-split CSR build (no high-contention atomics)
  hist2_k <<<EBLK, 256, 0, stream>>>(ei, cnt, btot);
  bscan2_k<<<1, 1024, 0, stream>>>(btot, bptr);
  bkpfx_k <<<NBK, 256, 0, stream>>>(cnt, bptr);
  scat2_k <<<EBLK, 256, 0, stream>>>(ei, cnt, ebuf);
  bcsr_k  <<<NBK, 256, 0, stream>>>(ebuf, bptr, rp, dinv, col, perm);

  wswz_all_k<<<dim3(32,6), 256, 0, stream>>>(W1,W2,W3,W4,W5,W6, W1s,W2s,W3s,W4s,W5s,W6s);
  f2q_k<<<(NN*128/4 + 255)/256, 256, 0, stream>>>(x, xq, NN*128/4);

  const int GX128 = NBK*16/4;   // W=128: 16 wave-groups/bucket, 4 waves/block = 3128
  const int GX64  = NBK*8/4;    // W=64:   8 wave-groups/bucket -> 1564
  const int GX    = (NN + 255)/256;    // gemm row-blocks (256 rows each)

  // L1: aggregate-first at width 128 (Â x, fp8 gather), then GEMM 128->256 (+b1, relu, bf16)
  spmm8_k<128,128,true,false,false><<<dim3(GX128,1),256,0,stream>>>(xq, hA, rp, col, dinv, perm, nullptr);
  mgemm_k<128,256,0><<<dim3(4,GX),256,0,stream>>>(hA, W1s, b1, hB, nullptr, NN);
  // L2: GEMM (*dinv -> fp8), spmm fp8 gather split into two 128-col slices (+b2, relu -> bf16)
  mgemm_k<256,256,1><<<dim3(4,GX),256,0,stream>>>(hB, W2s, dinv, nullptr, hQ, NN);
  spmm8_k<256,128,false,true,true><<<dim3(GX128,2),256,0,stream>>>(hQ, hA, rp, col, dinv, perm, b2);
  // L3
  mgemm_k<256,256,1><<<dim3(4,GX),256,0,stream>>>(hA, W3s, dinv, nullptr, hQ, NN);
  spmm8_k<256,128,false,true,true><<<dim3(GX128,2),256,0,stream>>>(hQ, hB, rp, col, dinv, perm, b3);
  // L4: 256->128
  mgemm_k<256,128,1><<<dim3(2,GX),256,0,stream>>>(hB, W4s, dinv, nullptr, hQ, NN);
  spmm8_k<128,128,false,true,true><<<dim3(GX128,1),256,0,stream>>>(hQ, hA, rp, col, dinv, perm, b4);
  // L5: 128->128
  mgemm_k<128,128,1><<<dim3(2,GX),256,0,stream>>>(hA, W5s, dinv, nullptr, hQ, NN);
  spmm8_k<128,128,false,true,true><<<dim3(GX128,1),256,0,stream>>>(hQ, hB, rp, col, dinv, perm, b5);
  // L6: 128->64, no relu
  mgemm_k<128,64,1><<<dim3(1,GX),256,0,stream>>>(hB, W6s, dinv, nullptr, hQ, NN);
  spmm8_k<64,64,false,false,true><<<dim3(GX64,1),256,0,stream>>>(hQ, hA, rp, col, dinv, perm, b6);

  // fused deterministic mean-pool + head
  poolhead_k<<<NG, 256, 0, stream>>>(hA, batch, Wl, bl, out);
}

// Round 6
// 1016.737 us; speedup vs baseline: 1.0536x; 1.0105x over previous
//
#include <hip/hip_runtime.h>
#include <math.h>

#define NN 100000
#define NE 3200000
#define NG 512
#define NBK 782            // dst buckets: ceil(NN/128), bucket = dst>>7
#define EBLK 196           // edge super-blocks: ceil(NE/16384)
#define SBE 16384          // edges per super-block
#define STSH 13            // src-tile shift: 8192-node tiles (1MB of a 128B/row slice)
#define NTIL 13            // ceil(NN / 8192)

typedef __attribute__((ext_vector_type(8))) short short8;
typedef __attribute__((ext_vector_type(4))) float f32x4;
typedef __attribute__((ext_vector_type(2))) float f32x2;

// ---------------- bf16 / fp8 helpers ----------------
__device__ __forceinline__ float bf2f(unsigned short h){
  return __uint_as_float(((unsigned int)h) << 16);
}
__device__ __forceinline__ unsigned short f2bf(float f){
  unsigned int u = __float_as_uint(f);
  unsigned int r = (u + 0x7fffu + ((u >> 16) & 1u)) >> 16;   // RNE
  return (unsigned short)r;
}
__device__ __forceinline__ unsigned char f2fp8(float v){
  int p = __builtin_amdgcn_cvt_pk_fp8_f32(v, v, 0, 0);
  return (unsigned char)p;
}

// ---------------- scan-based multi-split CSR build ----------------
// ebuf entries are PACKED: src (17 bits) | dst-within-bucket (7 bits) << 17.
// Super-block histogram (16384 edges/block): EBLK=196 so bkpfx is a single
// 256-wide scan pass and scat2 writes ~84B contiguous per bucket-region.
__global__ __launch_bounds__(256) void hist2_k(const int* __restrict__ ei,
    int* __restrict__ cnt, int* __restrict__ btot){
  __shared__ int lh[NBK];
  int t = threadIdx.x, b = blockIdx.x;
  for (int i=t; i<NBK; i+=256) lh[i] = 0;
  __syncthreads();
  int base = b*SBE;
  #pragma unroll 8
  for (int u=0; u<SBE/256; u++){
    int e = base + u*256 + t;
    if (e < NE) atomicAdd(&lh[ei[NE + e] >> 7], 1);
  }
  __syncthreads();
  for (int i=t; i<NBK; i+=256){
    int v = lh[i];
    cnt[b*NBK + i] = v;
    if (v) atomicAdd(&btot[i], v);
  }
}
__global__ void bscan2_k(const int* __restrict__ btot, int* __restrict__ bptr){
  __shared__ int sc[1024];
  int t = threadIdx.x;
  int v = (t < NBK) ? btot[t] : 0;
  sc[t] = v; __syncthreads();
  for (int off=1; off<1024; off<<=1){
    int u = (t>=off) ? sc[t-off] : 0;
    __syncthreads(); sc[t] += u; __syncthreads();
  }
  if (t < NBK) bptr[t] = sc[t] - v;
  if (t == 1023) bptr[NBK] = sc[1023];
}
// per-bucket exclusive scan over the 196 super-block counts: single pass (196<=256)
__global__ __launch_bounds__(256) void bkpfx_k(int* __restrict__ cnt, const int* __restrict__ bptr){
  __shared__ int sc[256];
  int b = blockIdx.x, t = threadIdx.x;
  int v = (t < EBLK) ? cnt[t*NBK + b] : 0;
  sc[t] = v; __syncthreads();
  for (int off=1; off<256; off<<=1){
    int u = (t>=off) ? sc[t-off] : 0;
    __syncthreads(); sc[t] += u; __syncthreads();
  }
  if (t < EBLK) cnt[t*NBK + b] = bptr[b] + sc[t] - v;   // exclusive + base
}
__global__ __launch_bounds__(256) void scat2_k(const int* __restrict__ ei,
    const int* __restrict__ cnt, unsigned int* __restrict__ ebuf){
  __shared__ int lh[NBK];
  __shared__ int lo[NBK];
  int t = threadIdx.x, b = blockIdx.x;
  for (int i=t; i<NBK; i+=256){ lh[i] = 0; lo[i] = cnt[b*NBK + i]; }
  __syncthreads();
  int base = b*SBE;
  #pragma unroll 8
  for (int u=0; u<SBE/256; u++){
    int e = base + u*256 + t;
    if (e < NE){
      int s = ei[e], d = ei[NE + e];
      int bk = d >> 7;
      int r = atomicAdd(&lh[bk], 1);
      ebuf[lo[bk] + r] = (unsigned)s | ((unsigned)(d & 127) << 17);
    }
  }
}
// fused per-bucket CSR finalize: per-(row,tile) count + scan -> rp/dinv/col, 2 passes
// over ebuf total. col layout is src-tile-grouped per row: tiles ascending within each
// row's edge segment. Also emits the degree-sorted row permutation (perm).
__global__ __launch_bounds__(256) void bcsr_k(const unsigned int* __restrict__ ebuf,
    const int* __restrict__ bptr, int* __restrict__ rp, float* __restrict__ dinv,
    int* __restrict__ col, int* __restrict__ permg){
  __shared__ int cnt2[128*NTIL];   // per (li,tile) counts -> absolute running offsets
  __shared__ int sc[128];
  __shared__ int dg[128];
  int b = blockIdx.x, t = threadIdx.x;
  int nbase = b << 7;
  int beg = bptr[b], end = bptr[b+1];
  for (int i = t; i < 128*NTIL; i += 256) cnt2[i] = 0;
  __syncthreads();
  for (int e = beg + t; e < end; e += 256){
    unsigned int sd = ebuf[e];
    int li = sd >> 17;
    int tile = (int)(sd & 0x1FFFFu) >> STSH;
    atomicAdd(&cnt2[li*NTIL + tile], 1);
  }
  __syncthreads();
  int v = 0;
  if (t < 128){
    #pragma unroll
    for (int k=0;k<NTIL;k++) v += cnt2[t*NTIL+k];
    sc[t] = v;
    dg[t] = ((nbase + t) < NN) ? v : 0x7FFFFFFF;   // invalid slots sort to bucket end
  }
  __syncthreads();
  for (int o2=1; o2<128; o2<<=1){
    int u = (t < 128 && t >= o2) ? sc[t-o2] : 0;
    __syncthreads();
    if (t < 128) sc[t] += u;
    __syncthreads();
  }
  if (t < 128){
    int node = nbase + t;
    int ex = beg + sc[t] - v;          // exclusive row start
    if (node < NN){
      rp[node] = ex;
      dinv[node] = rsqrtf((float)(v + 1));
    }
    // convert this row's tile counts into absolute running start offsets
    int s = ex;
    #pragma unroll
    for (int k=0;k<NTIL;k++){
      int c = cnt2[t*NTIL+k];
      cnt2[t*NTIL+k] = s;
      s += c;
    }
    // rank of this row by (degree, index) -> degree-sorted perm within bucket
    int d = dg[t];
    int rk = 0;
    #pragma unroll 4
    for (int u2=0; u2<128; u2++){
      int du = dg[u2];
      rk += (int)((du < d) || (du == d && u2 < t));
    }
    permg[nbase + rk] = node;    // node >= NN for pad slots; spmm guards row>=NN
  }
  if (b == ((NN-1) >> 7) && t == 0) rp[NN] = end;
  __syncthreads();
  for (int e = beg + t; e < end; e += 256){
    unsigned int sd = ebuf[e];
    int li = sd >> 17;
    int src = (int)(sd & 0x1FFFF);
    int tile = src >> STSH;
    int pos = atomicAdd(&cnt2[li*NTIL + tile], 1);
    col[pos] = src;
  }
}

// fp32 -> fp8 (4 values/thread)
__global__ void f2q_k(const float* __restrict__ in, unsigned char* __restrict__ out, int n4){
  int i = blockIdx.x*256 + threadIdx.x;
  if (i < n4){
    float4 v = ((const float4*)in)[i];
    int p = __builtin_amdgcn_cvt_pk_fp8_f32(v.x, v.y, 0, 0);
    p = __builtin_amdgcn_cvt_pk_fp8_f32(v.z, v.w, p, 1);
    ((unsigned int*)out)[i] = (unsigned int)p;
  }
}
// all 6 weight swizzles in one launch. blockIdx.y selects config.
// chunk idx = ((kt*(N/16)+nt)*4+q)*16 + l  holds B[k=kt*32+q*8+j][n=nt*16+l], j=0..7
__global__ void wswz_all_k(const float* W1, const float* W2, const float* W3,
                           const float* W4, const float* W5, const float* W6,
                           unsigned short* O1, unsigned short* O2, unsigned short* O3,
                           unsigned short* O4, unsigned short* O5, unsigned short* O6){
  int cfg = blockIdx.y;
  int K, N; const float* W; unsigned short* out;
  switch(cfg){
    case 0: K=128; N=256; W=W1; out=O1; break;
    case 1: K=256; N=256; W=W2; out=O2; break;
    case 2: K=256; N=256; W=W3; out=O3; break;
    case 3: K=256; N=128; W=W4; out=O4; break;
    case 4: K=128; N=128; W=W5; out=O5; break;
    default:K=128; N=64;  W=W6; out=O6; break;
  }
  int idx = blockIdx.x*256 + threadIdx.x;
  int total = K*N/8;
  if (idx >= total) return;
  int l = idx & 15;
  int t = idx >> 4; int q = t & 3; t >>= 2;
  int NT = N/16;
  int nt = t % NT, kt = t / NT;
  int kbase = kt*32 + q*8, n = nt*16 + l;
  short8 o;
  #pragma unroll
  for (int j=0;j<8;j++) o[j] = (short)f2bf(W[(size_t)(kbase+j)*N + n]);
  *(short8*)(out + (size_t)idx*8) = o;
}

// ---------------- fp8 SpMM (packed-pair FMA + LPT wave scheduling) ----------------
// RS = full row stride, W = columns handled by this dispatch slice (blockIdx.y).
// perm[] = rows sorted by degree within each 128-row dst bucket.
// Wave G = blockIdx.x*4+wv handles bucket G%NBK, rank-group (GP-1 - G/NBK):
// high-degree groups go to the EARLIEST blocks (LPT scheduling). Intra-wave rows are
// adjacent ranks (near-equal degree). Edges are src-tile-ordered (see bcsr_k).
// Accumulation is f32x2 packed (v_pk_fma_f32): 16 VALU instrs/edge vs 24 scalar.
// NOTE (R1-R5 evidence): this gather loop is pinned at ~3.6-3.7 TB/s on the L2-miss
// path across occupancies 26%-75% and three edge orderings -> structural ceiling for
// random 128B-line gathers. Do not touch.
template<int RS, int W, bool SRC_SCALE, bool RELU, bool HAS_BIAS>
__global__ __launch_bounds__(256) void spmm8_k(const unsigned char* __restrict__ in,
    unsigned short* __restrict__ out,
    const int* __restrict__ rp, const int* __restrict__ col,
    const float* __restrict__ dinv, const int* __restrict__ perm,
    const float* __restrict__ bias)
{
  constexpr int LPR = W/16;         // lanes per row
  constexpr int RPW = 64/LPR;       // rows per wave
  constexpr int GP  = 128/RPW;      // rank-groups per bucket
  int tid = threadIdx.x;
  int wv = tid >> 6, lane = tid & 63;
  int sub = lane / LPR, li = lane % LPR;
  int G = blockIdx.x*4 + wv;        // wave linear id over NBK*GP groups
  int bucket = G % NBK;
  int rg = (GP-1) - (G / NBK);      // descending degree: LPT
  int row = perm[(bucket << 7) + rg*RPW + sub];
  if (row >= NN) return;
  int beg = rp[row], end = rp[row+1];
  float di = dinv[row];
  int co = blockIdx.y*W + li*16;
  const unsigned char* inb = in + co;
  f32x2 acc2[8];
  {
    uint4 sv = *(const uint4*)(inb + (size_t)row*RS);   // self loop
    acc2[0] = __builtin_amdgcn_cvt_pk_f32_fp8(sv.x, 0);
    acc2[1] = __builtin_amdgcn_cvt_pk_f32_fp8(sv.x, 1);
    acc2[2] = __builtin_amdgcn_cvt_pk_f32_fp8(sv.y, 0);
    acc2[3] = __builtin_amdgcn_cvt_pk_f32_fp8(sv.y, 1);
    acc2[4] = __builtin_amdgcn_cvt_pk_f32_fp8(sv.z, 0);
    acc2[5] = __builtin_amdgcn_cvt_pk_f32_fp8(sv.z, 1);
    acc2[6] = __builtin_amdgcn_cvt_pk_f32_fp8(sv.w, 0);
    acc2[7] = __builtin_amdgcn_cvt_pk_f32_fp8(sv.w, 1);
    if (SRC_SCALE){
      f32x2 d2 = (f32x2){di, di};
      #pragma unroll
      for (int k=0;k<8;k++) acc2[k] = acc2[k] * d2;
    }
  }
  int j = beg;
  for (; j+8 <= end; j += 8){
    int s[8]; uint4 v[8]; float wgt[8];
    #pragma unroll
    for (int u=0;u<8;u++) s[u] = col[j+u];
    #pragma unroll
    for (int u=0;u<8;u++) v[u] = *(const uint4*)(inb + (size_t)s[u]*RS);
    if (SRC_SCALE){
      #pragma unroll
      for (int u=0;u<8;u++) wgt[u] = dinv[s[u]];
    }
    #pragma unroll
    for (int u=0;u<8;u++){
      float w = SRC_SCALE ? wgt[u] : 1.f;
      f32x2 w2 = (f32x2){w, w};
      acc2[0] = __builtin_elementwise_fma(w2, __builtin_amdgcn_cvt_pk_f32_fp8(v[u].x, 0), acc2[0]);
      acc2[1] = __builtin_elementwise_fma(w2, __builtin_amdgcn_cvt_pk_f32_fp8(v[u].x, 1), acc2[1]);
      acc2[2] = __builtin_elementwise_fma(w2, __builtin_amdgcn_cvt_pk_f32_fp8(v[u].y, 0), acc2[2]);
      acc2[3] = __builtin_elementwise_fma(w2, __builtin_amdgcn_cvt_pk_f32_fp8(v[u].y, 1), acc2[3]);
      acc2[4] = __builtin_elementwise_fma(w2, __builtin_amdgcn_cvt_pk_f32_fp8(v[u].z, 0), acc2[4]);
      acc2[5] = __builtin_elementwise_fma(w2, __builtin_amdgcn_cvt_pk_f32_fp8(v[u].z, 1), acc2[5]);
      acc2[6] = __builtin_elementwise_fma(w2, __builtin_amdgcn_cvt_pk_f32_fp8(v[u].w, 0), acc2[6]);
      acc2[7] = __builtin_elementwise_fma(w2, __builtin_amdgcn_cvt_pk_f32_fp8(v[u].w, 1), acc2[7]);
    }
  }
  for (; j < end; j++){
    int ss = col[j];
    uint4 v = *(const uint4*)(inb + (size_t)ss*RS);
    float w = SRC_SCALE ? dinv[ss] : 1.f;
    f32x2 w2 = (f32x2){w, w};
    acc2[0] = __builtin_elementwise_fma(w2, __builtin_amdgcn_cvt_pk_f32_fp8(v.x, 0), acc2[0]);
    acc2[1] = __builtin_elementwise_fma(w2, __builtin_amdgcn_cvt_pk_f32_fp8(v.x, 1), acc2[1]);
    acc2[2] = __builtin_elementwise_fma(w2, __builtin_amdgcn_cvt_pk_f32_fp8(v.y, 0), acc2[2]);
    acc2[3] = __builtin_elementwise_fma(w2, __builtin_amdgcn_cvt_pk_f32_fp8(v.y, 1), acc2[3]);
    acc2[4] = __builtin_elementwise_fma(w2, __builtin_amdgcn_cvt_pk_f32_fp8(v.z, 0), acc2[4]);
    acc2[5] = __builtin_elementwise_fma(w2, __builtin_amdgcn_cvt_pk_f32_fp8(v.z, 1), acc2[5]);
    acc2[6] = __builtin_elementwise_fma(w2, __builtin_amdgcn_cvt_pk_f32_fp8(v.w, 0), acc2[6]);
    acc2[7] = __builtin_elementwise_fma(w2, __builtin_amdgcn_cvt_pk_f32_fp8(v.w, 1), acc2[7]);
  }
  float acc[16];
  #pragma unroll
  for (int k=0;k<8;k++){ acc[2*k] = acc2[k][0]; acc[2*k+1] = acc2[k][1]; }
  float bb[16];
  if (HAS_BIAS){
    #pragma unroll
    for (int u=0;u<4;u++) *(float4*)&bb[u*4] = *(const float4*)(bias + co + u*4);
  }
  #pragma unroll
  for (int v=0;v<16;v++){
    acc[v] *= di;
    if (HAS_BIAS) acc[v] += bb[v];
    if (RELU) acc[v] = fmaxf(acc[v], 0.f);
  }
  uint4 o0, o1;
  o0.x = (unsigned int)f2bf(acc[0])  | ((unsigned int)f2bf(acc[1])<<16);
  o0.y = (unsigned int)f2bf(acc[2])  | ((unsigned int)f2bf(acc[3])<<16);
  o0.z = (unsigned int)f2bf(acc[4])  | ((unsigned int)f2bf(acc[5])<<16);
  o0.w = (unsigned int)f2bf(acc[6])  | ((unsigned int)f2bf(acc[7])<<16);
  o1.x = (unsigned int)f2bf(acc[8])  | ((unsigned int)f2bf(acc[9])<<16);
  o1.y = (unsigned int)f2bf(acc[10]) | ((unsigned int)f2bf(acc[11])<<16);
  o1.z = (unsigned int)f2bf(acc[12]) | ((unsigned int)f2bf(acc[13])<<16);
  o1.w = (unsigned int)f2bf(acc[14]) | ((unsigned int)f2bf(acc[15])<<16);
  unsigned short* op = out + (size_t)row*RS + co;
  *(uint4*)op = o0;
  *(uint4*)(op + 8) = o1;
}

// ---------------- MFMA bf16 GEMM, stage-once B slice, barrier-free K-loop ----------------
// Grid = dim3(N/64, GX): col-slices vary FASTEST, so the 4 slices sharing one A row-tile
// run concurrently and A re-reads hit L2/L3 instead of HBM.
// Block: 4 waves, 256 rows, 64 cols. K x 64 B-slice (<=32KB LDS) staged once, one barrier,
// then a barrier-free K-loop: 4 ds_read_b128 + 4 prefetched A loads + 16 MFMAs per kt/wave.
// EPI=0: +bias,relu,bf16.  EPI=1: *dinv[row], fp8.
template<int K, int N, int EPI>
__global__ __launch_bounds__(256) void mgemm_k(const unsigned short* __restrict__ A,
    const unsigned short* __restrict__ Bsw,
    const float* __restrict__ aux, unsigned short* __restrict__ Cb,
    unsigned char* __restrict__ Cq, int M)
{
  constexpr int NT = 4;                   // 64 cols = 4 n-tiles
  constexpr int KT = K/32;
  constexpr int NTF = N/16;               // n-tiles in full Bsw
  __shared__ short8 Bl[KT*NT*64];         // K x 64 slice: KT*4*64 short8 = K*64*2 B
  int tid = threadIdx.x;
  int w = tid >> 6, lane = tid & 63;
  int l = lane & 15, q = lane >> 4;
  int nb0 = blockIdx.x * 64;              // col slice (fastest)
  int rb = blockIdx.y*256 + w*64;         // row block
  // stage whole B slice (one barrier)
  {
    const short8* bsrc = (const short8*)Bsw;
    for (int i = tid; i < KT*NT*64; i += 256){
      int kt = i >> 8;                    // /(NT*64)
      int rem = i & 255;
      Bl[i] = bsrc[(kt*NTF + (nb0 >> 4))*64 + rem];
    }
  }
  const unsigned short* ap[4];
  #pragma unroll
  for (int rt=0; rt<4; rt++){
    int r = min(rb + rt*16 + l, M-1);
    ap[rt] = A + (size_t)r*K + q*8;
  }
  f32x4 acc[4][NT];
  #pragma unroll
  for (int rt=0; rt<4; rt++)
    #pragma unroll
    for (int nt=0; nt<NT; nt++) acc[rt][nt] = (f32x4){0,0,0,0};
  short8 a[4], an[4];
  #pragma unroll
  for (int rt=0; rt<4; rt++) a[rt] = *(const short8*)(ap[rt]);
  __syncthreads();
  for (int kt=0; kt<KT; kt++){
    if (kt+1 < KT){
      #pragma unroll
      for (int rt=0; rt<4; rt++) an[rt] = *(const short8*)(ap[rt] + (kt+1)*32);
    }
    const short8* bl = &Bl[kt << 8];
    #pragma unroll
    for (int nt=0; nt<NT; nt++){
      short8 bf = bl[nt*64 + q*16 + l];
      acc[0][nt] = __builtin_amdgcn_mfma_f32_16x16x32_bf16(a[0], bf, acc[0][nt], 0,0,0);
      acc[1][nt] = __builtin_amdgcn_mfma_f32_16x16x32_bf16(a[1], bf, acc[1][nt], 0,0,0);
      acc[2][nt] = __builtin_amdgcn_mfma_f32_16x16x32_bf16(a[2], bf, acc[2][nt], 0,0,0);
      acc[3][nt] = __builtin_amdgcn_mfma_f32_16x16x32_bf16(a[3], bf, acc[3][nt], 0,0,0);
    }
    #pragma unroll
    for (int rt=0; rt<4; rt++) a[rt] = an[rt];
  }
  #pragma unroll
  for (int rt=0; rt<4; rt++){
    int rbb = rb + rt*16;
    #pragma unroll
    for (int nt=0; nt<NT; nt++){
      f32x4 av = acc[rt][nt];
      int n = nb0 + nt*16 + l;
      #pragma unroll
      for (int r=0;r<4;r++){
        int row = rbb + q*4 + r;
        if (row < M){
          float v = av[r];
          if (EPI == 0){
            v = fmaxf(v + aux[n], 0.f);
            Cb[(size_t)row*N + n] = f2bf(v);
          } else {
            v *= aux[row];
            Cq[(size_t)row*N + n] = f2fp8(v);
          }
        }
      }
    }
  }
}

// ---------------- fused mean-pool + linear + (log_)softmax (batch sorted) ----------------
__global__ __launch_bounds__(256) void poolhead_k(const unsigned short* __restrict__ h,
    const int* __restrict__ batch, const float* __restrict__ Wlin,
    const float* __restrict__ blin, float* __restrict__ out)
{
  __shared__ int range[2];
  __shared__ float red[4][64];
  __shared__ float pl[64];
  int g = blockIdx.x;
  if (threadIdx.x < 2){
    int target = g + threadIdx.x;      // lower_bound(batch, target)
    int lo = 0, hi = NN;
    while (lo < hi){ int m = (lo+hi) >> 1; if (batch[m] < target) lo = m+1; else hi = m; }
    range[threadIdx.x] = lo;
  }
  __syncthreads();
  int lo = range[0], hi = range[1];
  int ch = threadIdx.x & 63, rg = threadIdx.x >> 6;
  float s = 0.f;
  for (int r = lo + rg; r < hi; r += 4) s += bf2f(h[(size_t)r*64 + ch]);
  red[rg][ch] = s; __syncthreads();
  if (rg == 0){
    float tot = red[0][ch] + red[1][ch] + red[2][ch] + red[3][ch];
    pl[ch] = tot / fmaxf((float)(hi - lo), 1.f);
  }
  __syncthreads();
  if (threadIdx.x == 0){
    float l[10];
    #pragma unroll
    for (int j=0;j<10;j++) l[j] = blin[j];
    for (int c=0;c<64;c++){
      float p = pl[c];
      #pragma unroll
      for (int j=0;j<10;j++) l[j] = fmaf(p, Wlin[c*10 + j], l[j]);
    }
    float mx = l[0];
    #pragma unroll
    for (int j=1;j<10;j++) mx = fmaxf(mx, l[j]);
    float e[10]; float se = 0.f;
    #pragma unroll
    for (int j=0;j<10;j++){ e[j] = expf(l[j]-mx); se += e[j]; }
    float lse = logf(se);
    #pragma unroll
    for (int j=0;j<10;j++){
      out[g*10 + j]         = l[j] - mx - lse;   // log_softmax
      out[NG*10 + g*10 + j] = e[j] / se;         // softmax
    }
  }
}

// ---------------- launch ----------------
extern "C" void kernel_launch(void* const* d_in, const int* in_sizes, int n_in,
                              void* d_out, int out_size, void* d_ws, size_t ws_size,
                              hipStream_t stream)
{
  const float* x     = (const float*)d_in[0];
  const int*   ei    = (const int*)  d_in[1];
  const int*   batch = (const int*)  d_in[2];
  const float* W1=(const float*)d_in[4],  *b1=(const float*)d_in[5];
  const float* W2=(const float*)d_in[6],  *b2=(const float*)d_in[7];
  const float* W3=(const float*)d_in[8],  *b3=(const float*)d_in[9];
  const float* W4=(const float*)d_in[10], *b4=(const float*)d_in[11];
  const float* W5=(const float*)d_in[12], *b5=(const float*)d_in[13];
  const float* W6=(const float*)d_in[14], *b6=(const float*)d_in[15];
  const float* Wl=(const float*)d_in[16], *bl=(const float*)d_in[17];
  float* out = (float*)d_out;

  char* ws = (char*)d_ws;
  unsigned short* hA  = (unsigned short*)(ws + 0);            // bf16 51,200,000
  unsigned short* hB  = (unsigned short*)(ws + 51200000);     // bf16 51,200,000
  unsigned char*  hQ  = (unsigned char*) (ws + 102400000);    // fp8  25,600,000
  unsigned char*  xq  = (unsigned char*) (ws + 128000000);    // fp8  12,800,000
  int*   col   = (int*)  (ws + 140800000);                    // 12,800,000
  unsigned int* ebuf = (unsigned int*)(ws + 153600000);       // 12,800,000 (packed)
  int*   rp    = (int*)  (ws + 166400000);                    // 400,016
  float* dinv  = (float*)(ws + 166800016);                    // 400,000
  unsigned short* W1s = (unsigned short*)(ws + 167200016);    // 65,536
  unsigned short* W2s = (unsigned short*)(ws + 167265552);    // 131,072
  unsigned short* W3s = (unsigned short*)(ws + 167396624);    // 131,072
  unsigned short* W4s = (unsigned short*)(ws + 167527696);    // 65,536
  unsigned short* W5s = (unsigned short*)(ws + 167593232);    // 32,768
  unsigned short* W6s = (unsigned short*)(ws + 167626000);    // 16,384
  int*   btot  = (int*)  (ws + 167642896);                    // 3,128
  int*   bptr  = (int*)  (ws + 167646032);                    // 3,132
  int*   cnt   = (int*)  (ws + 167649184);                    // 196*782*4 = 613,088 (region 2.4MB)
  // perm overlaps cnt: cnt's last reader is scat2_k, bcsr_k (writer of perm) runs after.
  int*   perm  = cnt;                                         // NBK*128 = 100,096 ints

  hipMemsetAsync(btot, 0, NBK*4, stream);

  // scan-based multi-split CSR build (no high-contention atomics)
  hist2_k <<<EBLK, 256, 0, stream>>>(ei, cnt, btot);
  bscan2_k<<<1, 1024, 0, stream>>>(btot, bptr);
  bkpfx_k <<<NBK, 256, 0, stream>>>(cnt, bptr);
  scat2_k <<<EBLK, 256, 0, stream>>>(ei, cnt, ebuf);
  bcsr_k  <<<NBK, 256, 0, stream>>>(ebuf, bptr, rp, dinv, col, perm);

  wswz_all_k<<<dim3(32,6), 256, 0, stream>>>(W1,W2,W3,W4,W5,W6, W1s,W2s,W3s,W4s,W5s,W6s);
  f2q_k<<<(NN*128/4 + 255)/256, 256, 0, stream>>>(x, xq, NN*128/4);

  const int GX128 = NBK*16/4;   // W=128: 16 wave-groups/bucket, 4 waves/block = 3128
  const int GX64  = NBK*8/4;    // W=64:   8 wave-groups/bucket -> 1564
  const int GX    = (NN + 255)/256;    // gemm row-blocks (256 rows each)

  // L1: aggregate-first at width 128 (Â x, fp8 gather), then GEMM 128->256 (+b1, relu, bf16)
  spmm8_k<128,128,true,false,false><<<dim3(GX128,1),256,0,stream>>>(xq, hA, rp, col, dinv, perm, nullptr);
  mgemm_k<128,256,0><<<dim3(4,GX),256,0,stream>>>(hA, W1s, b1, hB, nullptr, NN);
  // L2: GEMM (*dinv -> fp8), spmm fp8 gather split into two 128-col slices (+b2, relu -> bf16)
  mgemm_k<256,256,1><<<dim3(4,GX),256,0,stream>>>(hB, W2s, dinv, nullptr, hQ, NN);
  spmm8_k<256,128,false,true,true><<<dim3(GX128,2),256,0,stream>>>(hQ, hA, rp, col, dinv, perm, b2);
  // L3
  mgemm_k<256,256,1><<<dim3(4,GX),256,0,stream>>>(hA, W3s, dinv, nullptr, hQ, NN);
  spmm8_k<256,128,false,true,true><<<dim3(GX128,2),256,0,stream>>>(hQ, hB, rp, col, dinv, perm, b3);
  // L4: 256->128
  mgemm_k<256,128,1><<<dim3(2,GX),256,0,stream>>>(hB, W4s, dinv, nullptr, hQ, NN);
  spmm8_k<128,128,false,true,true><<<dim3(GX128,1),256,0,stream>>>(hQ, hA, rp, col, dinv, perm, b4);
  // L5: 128->128
  mgemm_k<128,128,1><<<dim3(2,GX),256,0,stream>>>(hA, W5s, dinv, nullptr, hQ, NN);
  spmm8_k<128,128,false,true,true><<<dim3(GX128,1),256,0,stream>>>(hQ, hB, rp, col, dinv, perm, b5);
  // L6: 128->64, no relu
  mgemm_k<128,64,1><<<dim3(1,GX),256,0,stream>>>(hB, W6s, dinv, nullptr, hQ, NN);
  spmm8_k<64,64,false,false,true><<<dim3(GX64,1),256,0,stream>>>(hQ, hA, rp, col, dinv, perm, b6);

  // fused deterministic mean-pool + head
  poolhead_k<<<NG, 256, 0, stream>>>(hA, batch, Wl, bl, out);
}

// Round 7
// 962.732 us; speedup vs baseline: 1.1127x; 1.0561x over previous
//
#include <hip/hip_runtime.h>
#include <math.h>

#define NN 100000
#define NE 3200000
#define NG 512
#define NBK 782            // dst buckets: ceil(NN/128), bucket = dst>>7
#define EBLK 196           // edge super-blocks: ceil(NE/16384)
#define SBE 16384          // edges per super-block
#define STSH 13            // src-tile shift: 8192-node tiles (1MB of a 128B/row slice)
#define NTIL 13            // ceil(NN / 8192)
#define HB 196             // pre_k: hist blocks
#define WB 192             // pre_k: wswz blocks (6 cfgs x 32)
#define QB 12500           // pre_k: f2q blocks (NN*128/4 / 256)

typedef __attribute__((ext_vector_type(8))) short short8;
typedef __attribute__((ext_vector_type(4))) float f32x4;
typedef __attribute__((ext_vector_type(2))) float f32x2;

// ---------------- bf16 / fp8 helpers ----------------
__device__ __forceinline__ float bf2f(unsigned short h){
  return __uint_as_float(((unsigned int)h) << 16);
}
__device__ __forceinline__ unsigned short f2bf(float f){
  unsigned int u = __float_as_uint(f);
  unsigned int r = (u + 0x7fffu + ((u >> 16) & 1u)) >> 16;   // RNE
  return (unsigned short)r;
}
__device__ __forceinline__ unsigned char f2fp8(float v){
  int p = __builtin_amdgcn_cvt_pk_fp8_f32(v, v, 0, 0);
  return (unsigned char)p;
}

// ---------------- fused pre-pass: hist + weight swizzle + x->fp8 (one launch) ----------
// Blocks [0,HB): per-super-block dst histogram (cnt, btot).
// Blocks [HB,HB+WB): all 6 weight swizzles (cfg = (b-HB)/32).
// Blocks [HB+WB, HB+WB+QB): fp32->fp8 of x (4 vals/thread).
// Independent work grid-fused to remove 2 dispatch gaps and overlap their traffic.
__global__ __launch_bounds__(256) void pre_k(const int* __restrict__ ei,
    int* __restrict__ cnt, int* __restrict__ btot,
    const float* __restrict__ x, unsigned char* __restrict__ xq,
    const float* W1, const float* W2, const float* W3,
    const float* W4, const float* W5, const float* W6,
    unsigned short* O1, unsigned short* O2, unsigned short* O3,
    unsigned short* O4, unsigned short* O5, unsigned short* O6)
{
  __shared__ int lh[NBK];
  int b = blockIdx.x, t = threadIdx.x;
  if (b < HB){
    for (int i=t; i<NBK; i+=256) lh[i] = 0;
    __syncthreads();
    int base = b*SBE;
    #pragma unroll 8
    for (int u=0; u<SBE/256; u++){
      int e = base + u*256 + t;
      if (e < NE) atomicAdd(&lh[ei[NE + e] >> 7], 1);
    }
    __syncthreads();
    for (int i=t; i<NBK; i+=256){
      int v = lh[i];
      cnt[b*NBK + i] = v;
      if (v) atomicAdd(&btot[i], v);
    }
    return;
  }
  if (b < HB + WB){
    int bb = b - HB;
    int cfg = bb >> 5, bx = bb & 31;
    int K, N; const float* W; unsigned short* out;
    switch(cfg){
      case 0: K=128; N=256; W=W1; out=O1; break;
      case 1: K=256; N=256; W=W2; out=O2; break;
      case 2: K=256; N=256; W=W3; out=O3; break;
      case 3: K=256; N=128; W=W4; out=O4; break;
      case 4: K=128; N=128; W=W5; out=O5; break;
      default:K=128; N=64;  W=W6; out=O6; break;
    }
    int idx = bx*256 + t;
    int total = K*N/8;
    if (idx >= total) return;
    int l = idx & 15;
    int tt = idx >> 4; int q = tt & 3; tt >>= 2;
    int NT = N/16;
    int nt = tt % NT, kt = tt / NT;
    int kbase = kt*32 + q*8, n = nt*16 + l;
    short8 o;
    #pragma unroll
    for (int j=0;j<8;j++) o[j] = (short)f2bf(W[(size_t)(kbase+j)*N + n]);
    *(short8*)(out + (size_t)idx*8) = o;
    return;
  }
  {
    int i = (b - HB - WB)*256 + t;      // QB*256 == NN*128/4 exactly
    float4 v = ((const float4*)x)[i];
    int p = __builtin_amdgcn_cvt_pk_fp8_f32(v.x, v.y, 0, 0);
    p = __builtin_amdgcn_cvt_pk_fp8_f32(v.z, v.w, p, 1);
    ((unsigned int*)xq)[i] = (unsigned int)p;
  }
}

// per-bucket scan, with the 782-wide bucket-base prefix fused in (replaces the old
// single-block bscan2 bubble): each block sums btot[0..b) itself (3KB, L2-resident).
__global__ __launch_bounds__(256) void bkpfx_k(int* __restrict__ cnt,
    const int* __restrict__ btot, int* __restrict__ bptr){
  __shared__ int sc[256];
  int b = blockIdx.x, t = threadIdx.x;
  int p = 0;
  for (int i = t; i < b; i += 256) p += btot[i];
  sc[t] = p; __syncthreads();
  for (int off=128; off>0; off>>=1){
    if (t < off) sc[t] += sc[t+off];
    __syncthreads();
  }
  int pb = sc[0];
  __syncthreads();
  if (t == 0){
    bptr[b] = pb;
    if (b == NBK-1) bptr[NBK] = pb + btot[b];
  }
  int v = (t < EBLK) ? cnt[t*NBK + b] : 0;
  sc[t] = v; __syncthreads();
  for (int off=1; off<256; off<<=1){
    int u = (t>=off) ? sc[t-off] : 0;
    __syncthreads(); sc[t] += u; __syncthreads();
  }
  if (t < EBLK) cnt[t*NBK + b] = pb + sc[t] - v;   // exclusive + base
}
__global__ __launch_bounds__(256) void scat2_k(const int* __restrict__ ei,
    const int* __restrict__ cnt, unsigned int* __restrict__ ebuf){
  __shared__ int lh[NBK];
  __shared__ int lo[NBK];
  int t = threadIdx.x, b = blockIdx.x;
  for (int i=t; i<NBK; i+=256){ lh[i] = 0; lo[i] = cnt[b*NBK + i]; }
  __syncthreads();
  int base = b*SBE;
  #pragma unroll 8
  for (int u=0; u<SBE/256; u++){
    int e = base + u*256 + t;
    if (e < NE){
      int s = ei[e], d = ei[NE + e];
      int bk = d >> 7;
      int r = atomicAdd(&lh[bk], 1);
      ebuf[lo[bk] + r] = (unsigned)s | ((unsigned)(d & 127) << 17);
    }
  }
}
// fused per-bucket CSR finalize: per-(row,tile) count + scan -> rp/dinv/col, 2 passes
// over ebuf total. col layout is src-tile-grouped per row: tiles ascending within each
// row's edge segment. Also emits the degree-sorted row permutation (perm).
__global__ __launch_bounds__(256) void bcsr_k(const unsigned int* __restrict__ ebuf,
    const int* __restrict__ bptr, int* __restrict__ rp, float* __restrict__ dinv,
    int* __restrict__ col, int* __restrict__ permg){
  __shared__ int cnt2[128*NTIL];   // per (li,tile) counts -> absolute running offsets
  __shared__ int sc[128];
  __shared__ int dg[128];
  int b = blockIdx.x, t = threadIdx.x;
  int nbase = b << 7;
  int beg = bptr[b], end = bptr[b+1];
  for (int i = t; i < 128*NTIL; i += 256) cnt2[i] = 0;
  __syncthreads();
  for (int e = beg + t; e < end; e += 256){
    unsigned int sd = ebuf[e];
    int li = sd >> 17;
    int tile = (int)(sd & 0x1FFFFu) >> STSH;
    atomicAdd(&cnt2[li*NTIL + tile], 1);
  }
  __syncthreads();
  int v = 0;
  if (t < 128){
    #pragma unroll
    for (int k=0;k<NTIL;k++) v += cnt2[t*NTIL+k];
    sc[t] = v;
    dg[t] = ((nbase + t) < NN) ? v : 0x7FFFFFFF;   // invalid slots sort to bucket end
  }
  __syncthreads();
  for (int o2=1; o2<128; o2<<=1){
    int u = (t < 128 && t >= o2) ? sc[t-o2] : 0;
    __syncthreads();
    if (t < 128) sc[t] += u;
    __syncthreads();
  }
  if (t < 128){
    int node = nbase + t;
    int ex = beg + sc[t] - v;          // exclusive row start
    if (node < NN){
      rp[node] = ex;
      dinv[node] = rsqrtf((float)(v + 1));
    }
    // convert this row's tile counts into absolute running start offsets
    int s = ex;
    #pragma unroll
    for (int k=0;k<NTIL;k++){
      int c = cnt2[t*NTIL+k];
      cnt2[t*NTIL+k] = s;
      s += c;
    }
    // rank of this row by (degree, index) -> degree-sorted perm within bucket
    int d = dg[t];
    int rk = 0;
    #pragma unroll 4
    for (int u2=0; u2<128; u2++){
      int du = dg[u2];
      rk += (int)((du < d) || (du == d && u2 < t));
    }
    permg[nbase + rk] = node;    // node >= NN for pad slots; spmm guards row>=NN
  }
  if (b == ((NN-1) >> 7) && t == 0) rp[NN] = end;
  __syncthreads();
  for (int e = beg + t; e < end; e += 256){
    unsigned int sd = ebuf[e];
    int li = sd >> 17;
    int src = (int)(sd & 0x1FFFF);
    int tile = src >> STSH;
    int pos = atomicAdd(&cnt2[li*NTIL + tile], 1);
    col[pos] = src;
  }
}

// ---------------- fp8 SpMM (packed-pair FMA + LPT wave scheduling) ----------------
// RS = full row stride, W = columns handled by this dispatch slice (blockIdx.y).
// perm[] = rows sorted by degree within each 128-row dst bucket.
// Wave G = blockIdx.x*4+wv handles bucket G%NBK, rank-group (GP-1 - G/NBK):
// high-degree groups go to the EARLIEST blocks (LPT scheduling). Intra-wave rows are
// adjacent ranks (near-equal degree). Edges are src-tile-ordered (see bcsr_k).
// Accumulation is f32x2 packed (v_pk_fma_f32): 16 VALU instrs/edge vs 24 scalar.
// NOTE (R1-R6 evidence): this gather loop is pinned at ~3.6-3.7 TB/s on the L2-miss
// path across occupancies 26%-75% and three edge orderings -> structural ceiling for
// random 128B-line gathers. Do not touch.
template<int RS, int W, bool SRC_SCALE, bool RELU, bool HAS_BIAS>
__global__ __launch_bounds__(256) void spmm8_k(const unsigned char* __restrict__ in,
    unsigned short* __restrict__ out,
    const int* __restrict__ rp, const int* __restrict__ col,
    const float* __restrict__ dinv, const int* __restrict__ perm,
    const float* __restrict__ bias)
{
  constexpr int LPR = W/16;         // lanes per row
  constexpr int RPW = 64/LPR;       // rows per wave
  constexpr int GP  = 128/RPW;      // rank-groups per bucket
  int tid = threadIdx.x;
  int wv = tid >> 6, lane = tid & 63;
  int sub = lane / LPR, li = lane % LPR;
  int G = blockIdx.x*4 + wv;        // wave linear id over NBK*GP groups
  int bucket = G % NBK;
  int rg = (GP-1) - (G / NBK);      // descending degree: LPT
  int row = perm[(bucket << 7) + rg*RPW + sub];
  if (row >= NN) return;
  int beg = rp[row], end = rp[row+1];
  float di = dinv[row];
  int co = blockIdx.y*W + li*16;
  const unsigned char* inb = in + co;
  f32x2 acc2[8];
  {
    uint4 sv = *(const uint4*)(inb + (size_t)row*RS);   // self loop
    acc2[0] = __builtin_amdgcn_cvt_pk_f32_fp8(sv.x, 0);
    acc2[1] = __builtin_amdgcn_cvt_pk_f32_fp8(sv.x, 1);
    acc2[2] = __builtin_amdgcn_cvt_pk_f32_fp8(sv.y, 0);
    acc2[3] = __builtin_amdgcn_cvt_pk_f32_fp8(sv.y, 1);
    acc2[4] = __builtin_amdgcn_cvt_pk_f32_fp8(sv.z, 0);
    acc2[5] = __builtin_amdgcn_cvt_pk_f32_fp8(sv.z, 1);
    acc2[6] = __builtin_amdgcn_cvt_pk_f32_fp8(sv.w, 0);
    acc2[7] = __builtin_amdgcn_cvt_pk_f32_fp8(sv.w, 1);
    if (SRC_SCALE){
      f32x2 d2 = (f32x2){di, di};
      #pragma unroll
      for (int k=0;k<8;k++) acc2[k] = acc2[k] * d2;
    }
  }
  int j = beg;
  for (; j+8 <= end; j += 8){
    int s[8]; uint4 v[8]; float wgt[8];
    #pragma unroll
    for (int u=0;u<8;u++) s[u] = col[j+u];
    #pragma unroll
    for (int u=0;u<8;u++) v[u] = *(const uint4*)(inb + (size_t)s[u]*RS);
    if (SRC_SCALE){
      #pragma unroll
      for (int u=0;u<8;u++) wgt[u] = dinv[s[u]];
    }
    #pragma unroll
    for (int u=0;u<8;u++){
      float w = SRC_SCALE ? wgt[u] : 1.f;
      f32x2 w2 = (f32x2){w, w};
      acc2[0] = __builtin_elementwise_fma(w2, __builtin_amdgcn_cvt_pk_f32_fp8(v[u].x, 0), acc2[0]);
      acc2[1] = __builtin_elementwise_fma(w2, __builtin_amdgcn_cvt_pk_f32_fp8(v[u].x, 1), acc2[1]);
      acc2[2] = __builtin_elementwise_fma(w2, __builtin_amdgcn_cvt_pk_f32_fp8(v[u].y, 0), acc2[2]);
      acc2[3] = __builtin_elementwise_fma(w2, __builtin_amdgcn_cvt_pk_f32_fp8(v[u].y, 1), acc2[3]);
      acc2[4] = __builtin_elementwise_fma(w2, __builtin_amdgcn_cvt_pk_f32_fp8(v[u].z, 0), acc2[4]);
      acc2[5] = __builtin_elementwise_fma(w2, __builtin_amdgcn_cvt_pk_f32_fp8(v[u].z, 1), acc2[5]);
      acc2[6] = __builtin_elementwise_fma(w2, __builtin_amdgcn_cvt_pk_f32_fp8(v[u].w, 0), acc2[6]);
      acc2[7] = __builtin_elementwise_fma(w2, __builtin_amdgcn_cvt_pk_f32_fp8(v[u].w, 1), acc2[7]);
    }
  }
  for (; j < end; j++){
    int ss = col[j];
    uint4 v = *(const uint4*)(inb + (size_t)ss*RS);
    float w = SRC_SCALE ? dinv[ss] : 1.f;
    f32x2 w2 = (f32x2){w, w};
    acc2[0] = __builtin_elementwise_fma(w2, __builtin_amdgcn_cvt_pk_f32_fp8(v.x, 0), acc2[0]);
    acc2[1] = __builtin_elementwise_fma(w2, __builtin_amdgcn_cvt_pk_f32_fp8(v.x, 1), acc2[1]);
    acc2[2] = __builtin_elementwise_fma(w2, __builtin_amdgcn_cvt_pk_f32_fp8(v.y, 0), acc2[2]);
    acc2[3] = __builtin_elementwise_fma(w2, __builtin_amdgcn_cvt_pk_f32_fp8(v.y, 1), acc2[3]);
    acc2[4] = __builtin_elementwise_fma(w2, __builtin_amdgcn_cvt_pk_f32_fp8(v.z, 0), acc2[4]);
    acc2[5] = __builtin_elementwise_fma(w2, __builtin_amdgcn_cvt_pk_f32_fp8(v.z, 1), acc2[5]);
    acc2[6] = __builtin_elementwise_fma(w2, __builtin_amdgcn_cvt_pk_f32_fp8(v.w, 0), acc2[6]);
    acc2[7] = __builtin_elementwise_fma(w2, __builtin_amdgcn_cvt_pk_f32_fp8(v.w, 1), acc2[7]);
  }
  float acc[16];
  #pragma unroll
  for (int k=0;k<8;k++){ acc[2*k] = acc2[k][0]; acc[2*k+1] = acc2[k][1]; }
  float bb[16];
  if (HAS_BIAS){
    #pragma unroll
    for (int u=0;u<4;u++) *(float4*)&bb[u*4] = *(const float4*)(bias + co + u*4);
  }
  #pragma unroll
  for (int v=0;v<16;v++){
    acc[v] *= di;
    if (HAS_BIAS) acc[v] += bb[v];
    if (RELU) acc[v] = fmaxf(acc[v], 0.f);
  }
  uint4 o0, o1;
  o0.x = (unsigned int)f2bf(acc[0])  | ((unsigned int)f2bf(acc[1])<<16);
  o0.y = (unsigned int)f2bf(acc[2])  | ((unsigned int)f2bf(acc[3])<<16);
  o0.z = (unsigned int)f2bf(acc[4])  | ((unsigned int)f2bf(acc[5])<<16);
  o0.w = (unsigned int)f2bf(acc[6])  | ((unsigned int)f2bf(acc[7])<<16);
  o1.x = (unsigned int)f2bf(acc[8])  | ((unsigned int)f2bf(acc[9])<<16);
  o1.y = (unsigned int)f2bf(acc[10]) | ((unsigned int)f2bf(acc[11])<<16);
  o1.z = (unsigned int)f2bf(acc[12]) | ((unsigned int)f2bf(acc[13])<<16);
  o1.w = (unsigned int)f2bf(acc[14]) | ((unsigned int)f2bf(acc[15])<<16);
  unsigned short* op = out + (size_t)row*RS + co;
  *(uint4*)op = o0;
  *(uint4*)(op + 8) = o1;
}

// ---------------- MFMA bf16 GEMM, stage-once B slice, barrier-free K-loop ----------------
// XCD-aware 1D grid: id%8 selects the XCD (round-robin dispatch heuristic);
// the NSL col-slices of one A row-tile get ids {k, k+8, .., k+8*(NSL-1)} -> SAME XCD,
// co-resident -> A row-tile is fetched into that XCD's L2 once and re-read NSL-1 times
// from L2 (previous slice-fastest 2D grid spread the slices over 4 XCDs, diluting L2).
// Block: 4 waves, 256 rows, 64 cols. K x 64 B-slice (<=32KB LDS) staged once, one barrier,
// then a barrier-free K-loop. EPI=0: +bias,relu,bf16.  EPI=1: *dinv[row], fp8.
template<int K, int N, int EPI>
__global__ __launch_bounds__(256) void mgemm_k(const unsigned short* __restrict__ A,
    const unsigned short* __restrict__ Bsw,
    const float* __restrict__ aux, unsigned short* __restrict__ Cb,
    unsigned char* __restrict__ Cq, int M)
{
  constexpr int NT = 4;                   // 64 cols = 4 n-tiles
  constexpr int KT = K/32;
  constexpr int NTF = N/16;               // n-tiles in full Bsw
  constexpr int NSL = N/64;               // col-slices
  __shared__ short8 Bl[KT*NT*64];         // K x 64 slice: KT*4*64 short8 = K*64*2 B
  int tid = threadIdx.x;
  int w = tid >> 6, lane = tid & 63;
  int l = lane & 15, q = lane >> 4;
  int id = blockIdx.x;
  int xcd = id & 7, s = id >> 3;
  int xsl = s % NSL;
  int y = (s / NSL)*8 + xcd;
  if (y >= (M + 255)/256) return;         // uniform per block
  int nb0 = xsl * 64;                     // col slice
  int rb = y*256 + w*64;                  // row block
  // stage whole B slice (one barrier)
  {
    const short8* bsrc = (const short8*)Bsw;
    for (int i = tid; i < KT*NT*64; i += 256){
      int kt = i >> 8;                    // /(NT*64)
      int rem = i & 255;
      Bl[i] = bsrc[(kt*NTF + (nb0 >> 4))*64 + rem];
    }
  }
  const unsigned short* ap[4];
  #pragma unroll
  for (int rt=0; rt<4; rt++){
    int r = min(rb + rt*16 + l, M-1);
    ap[rt] = A + (size_t)r*K + q*8;
  }
  f32x4 acc[4][NT];
  #pragma unroll
  for (int rt=0; rt<4; rt++)
    #pragma unroll
    for (int nt=0; nt<NT; nt++) acc[rt][nt] = (f32x4){0,0,0,0};
  short8 a[4], an[4];
  #pragma unroll
  for (int rt=0; rt<4; rt++) a[rt] = *(const short8*)(ap[rt]);
  __syncthreads();
  for (int kt=0; kt<KT; kt++){
    if (kt+1 < KT){
      #pragma unroll
      for (int rt=0; rt<4; rt++) an[rt] = *(const short8*)(ap[rt] + (kt+1)*32);
    }
    const short8* bl = &Bl[kt << 8];
    #pragma unroll
    for (int nt=0; nt<NT; nt++){
      short8 bf = bl[nt*64 + q*16 + l];
      acc[0][nt] = __builtin_amdgcn_mfma_f32_16x16x32_bf16(a[0], bf, acc[0][nt], 0,0,0);
      acc[1][nt] = __builtin_amdgcn_mfma_f32_16x16x32_bf16(a[1], bf, acc[1][nt], 0,0,0);
      acc[2][nt] = __builtin_amdgcn_mfma_f32_16x16x32_bf16(a[2], bf, acc[2][nt], 0,0,0);
      acc[3][nt] = __builtin_amdgcn_mfma_f32_16x16x32_bf16(a[3], bf, acc[3][nt], 0,0,0);
    }
    #pragma unroll
    for (int rt=0; rt<4; rt++) a[rt] = an[rt];
  }
  #pragma unroll
  for (int rt=0; rt<4; rt++){
    int rbb = rb + rt*16;
    #pragma unroll
    for (int nt=0; nt<NT; nt++){
      f32x4 av = acc[rt][nt];
      int n = nb0 + nt*16 + l;
      #pragma unroll
      for (int r=0;r<4;r++){
        int row = rbb + q*4 + r;
        if (row < M){
          float v = av[r];
          if (EPI == 0){
            v = fmaxf(v + aux[n], 0.f);
            Cb[(size_t)row*N + n] = f2bf(v);
          } else {
            v *= aux[row];
            Cq[(size_t)row*N + n] = f2fp8(v);
          }
        }
      }
    }
  }
}

// ---------------- fused mean-pool + linear + (log_)softmax (batch sorted) ----------------
__global__ __launch_bounds__(256) void poolhead_k(const unsigned short* __restrict__ h,
    const int* __restrict__ batch, const float* __restrict__ Wlin,
    const float* __restrict__ blin, float* __restrict__ out)
{
  __shared__ int range[2];
  __shared__ float red[4][64];
  __shared__ float pl[64];
  int g = blockIdx.x;
  if (threadIdx.x < 2){
    int target = g + threadIdx.x;      // lower_bound(batch, target)
    int lo = 0, hi = NN;
    while (lo < hi){ int m = (lo+hi) >> 1; if (batch[m] < target) lo = m+1; else hi = m; }
    range[threadIdx.x] = lo;
  }
  __syncthreads();
  int lo = range[0], hi = range[1];
  int ch = threadIdx.x & 63, rg = threadIdx.x >> 6;
  float s = 0.f;
  for (int r = lo + rg; r < hi; r += 4) s += bf2f(h[(size_t)r*64 + ch]);
  red[rg][ch] = s; __syncthreads();
  if (rg == 0){
    float tot = red[0][ch] + red[1][ch] + red[2][ch] + red[3][ch];
    pl[ch] = tot / fmaxf((float)(hi - lo), 1.f);
  }
  __syncthreads();
  if (threadIdx.x == 0){
    float l[10];
    #pragma unroll
    for (int j=0;j<10;j++) l[j] = blin[j];
    for (int c=0;c<64;c++){
      float p = pl[c];
      #pragma unroll
      for (int j=0;j<10;j++) l[j] = fmaf(p, Wlin[c*10 + j], l[j]);
    }
    float mx = l[0];
    #pragma unroll
    for (int j=1;j<10;j++) mx = fmaxf(mx, l[j]);
    float e[10]; float se = 0.f;
    #pragma unroll
    for (int j=0;j<10;j++){ e[j] = expf(l[j]-mx); se += e[j]; }
    float lse = logf(se);
    #pragma unroll
    for (int j=0;j<10;j++){
      out[g*10 + j]         = l[j] - mx - lse;   // log_softmax
      out[NG*10 + g*10 + j] = e[j] / se;         // softmax
    }
  }
}

// ---------------- launch ----------------
extern "C" void kernel_launch(void* const* d_in, const int* in_sizes, int n_in,
                              void* d_out, int out_size, void* d_ws, size_t ws_size,
                              hipStream_t stream)
{
  const float* x     = (const float*)d_in[0];
  const int*   ei    = (const int*)  d_in[1];
  const int*   batch = (const int*)  d_in[2];
  const float* W1=(const float*)d_in[4],  *b1=(const float*)d_in[5];
  const float* W2=(const float*)d_in[6],  *b2=(const float*)d_in[7];
  const float* W3=(const float*)d_in[8],  *b3=(const float*)d_in[9];
  const float* W4=(const float*)d_in[10], *b4=(const float*)d_in[11];
  const float* W5=(const float*)d_in[12], *b5=(const float*)d_in[13];
  const float* W6=(const float*)d_in[14], *b6=(const float*)d_in[15];
  const float* Wl=(const float*)d_in[16], *bl=(const float*)d_in[17];
  float* out = (float*)d_out;

  char* ws = (char*)d_ws;
  unsigned short* hA  = (unsigned short*)(ws + 0);            // bf16 51,200,000
  unsigned short* hB  = (unsigned short*)(ws + 51200000);     // bf16 51,200,000
  unsigned char*  hQ  = (unsigned char*) (ws + 102400000);    // fp8  25,600,000
  unsigned char*  xq  = (unsigned char*) (ws + 128000000);    // fp8  12,800,000
  int*   col   = (int*)  (ws + 140800000);                    // 12,800,000
  unsigned int* ebuf = (unsigned int*)(ws + 153600000);       // 12,800,000 (packed)
  int*   rp    = (int*)  (ws + 166400000);                    // 400,016
  float* dinv  = (float*)(ws + 166800016);                    // 400,000
  unsigned short* W1s = (unsigned short*)(ws + 167200016);    // 65,536
  unsigned short* W2s = (unsigned short*)(ws + 167265552);    // 131,072
  unsigned short* W3s = (unsigned short*)(ws + 167396624);    // 131,072
  unsigned short* W4s = (unsigned short*)(ws + 167527696);    // 65,536
  unsigned short* W5s = (unsigned short*)(ws + 167593232);    // 32,768
  unsigned short* W6s = (unsigned short*)(ws + 167626000);    // 16,384
  int*   btot  = (int*)  (ws + 167642896);                    // 3,128
  int*   bptr  = (int*)  (ws + 167646032);                    // 3,132
  int*   cnt   = (int*)  (ws + 167649184);                    // 196*782*4 = 613,088
  // perm overlaps cnt: cnt's last reader is scat2_k, bcsr_k (writer of perm) runs after.
  int*   perm  = cnt;                                         // NBK*128 = 100,096 ints

  hipMemsetAsync(btot, 0, NBK*4, stream);

  // fused pre-pass (hist + wswz + f2q), then scan-based multi-split CSR build
  pre_k <<<HB+WB+QB, 256, 0, stream>>>(ei, cnt, btot, x, xq,
      W1,W2,W3,W4,W5,W6, W1s,W2s,W3s,W4s,W5s,W6s);
  bkpfx_k <<<NBK, 256, 0, stream>>>(cnt, btot, bptr);
  scat2_k <<<EBLK, 256, 0, stream>>>(ei, cnt, ebuf);
  bcsr_k  <<<NBK, 256, 0, stream>>>(ebuf, bptr, rp, dinv, col, perm);

  const int GX128 = NBK*16/4;   // W=128: 16 wave-groups/bucket, 4 waves/block = 3128
  const int GX64  = NBK*8/4;    // W=64:   8 wave-groups/bucket -> 1564
  const int GT    = (NN + 255)/256;    // gemm row-tiles (391)
  const int GY8   = (GT + 7)/8;        // row-tiles per XCD stripe (49)
  const int G256  = 8*4*GY8;           // N=256: 1568 blocks
  const int G128  = 8*2*GY8;           // N=128: 784
  const int G64   = 8*1*GY8;           // N=64:  392

  // L1: aggregate-first at width 128 (Â x, fp8 gather), then GEMM 128->256 (+b1, relu, bf16)
  spmm8_k<128,128,true,false,false><<<dim3(GX128,1),256,0,stream>>>(xq, hA, rp, col, dinv, perm, nullptr);
  mgemm_k<128,256,0><<<G256,256,0,stream>>>(hA, W1s, b1, hB, nullptr, NN);
  // L2: GEMM (*dinv -> fp8), spmm fp8 gather split into two 128-col slices (+b2, relu -> bf16)
  mgemm_k<256,256,1><<<G256,256,0,stream>>>(hB, W2s, dinv, nullptr, hQ, NN);
  spmm8_k<256,128,false,true,true><<<dim3(GX128,2),256,0,stream>>>(hQ, hA, rp, col, dinv, perm, b2);
  // L3
  mgemm_k<256,256,1><<<G256,256,0,stream>>>(hA, W3s, dinv, nullptr, hQ, NN);
  spmm8_k<256,128,false,true,true><<<dim3(GX128,2),256,0,stream>>>(hQ, hB, rp, col, dinv, perm, b3);
  // L4: 256->128
  mgemm_k<256,128,1><<<G128,256,0,stream>>>(hB, W4s, dinv, nullptr, hQ, NN);
  spmm8_k<128,128,false,true,true><<<dim3(GX128,1),256,0,stream>>>(hQ, hA, rp, col, dinv, perm, b4);
  // L5: 128->128
  mgemm_k<128,128,1><<<G128,256,0,stream>>>(hA, W5s, dinv, nullptr, hQ, NN);
  spmm8_k<128,128,false,true,true><<<dim3(GX128,1),256,0,stream>>>(hQ, hB, rp, col, dinv, perm, b5);
  // L6: 128->64, no relu
  mgemm_k<128,64,1><<<G64,256,0,stream>>>(hB, W6s, dinv, nullptr, hQ, NN);
  spmm8_k<64,64,false,false,true><<<dim3(GX64,1),256,0,stream>>>(hQ, hA, rp, col, dinv, perm, b6);

  // fused deterministic mean-pool + head
  poolhead_k<<<NG, 256, 0, stream>>>(hA, batch, Wl, bl, out);
}